// Round 1
// baseline (5972.109 us; speedup 1.0000x reference)
//
#include <hip/hip_runtime.h>
#include <hip/hip_bf16.h>
#include <math.h>

// Problem constants (verified against in_sizes at launch)
#define DIM 128
#define HID 256

// ---------------------------------------------------------------------------
// degree: deg[src[e]] += 1
__global__ void deg_kernel(const int* __restrict__ src, float* __restrict__ deg, int nE) {
    int e = blockIdx.x * blockDim.x + threadIdx.x;
    if (e < nE) atomicAdd(&deg[src[e]], 1.0f);
}

// coef[e] = rsqrt(deg[src]*deg[dst])
__global__ void coef_kernel(const int* __restrict__ src, const int* __restrict__ dst,
                            const float* __restrict__ deg, float* __restrict__ coef, int nE) {
    int e = blockIdx.x * blockDim.x + threadIdx.x;
    if (e < nE) coef[e] = rsqrtf(deg[src[e]] * deg[dst[e]]);
}

// forward rotation: h0[n,b,c,e] = sum_d R[n,b,c,d] * x[n,b,d,e]
__global__ void rot_kernel(const float* __restrict__ x, const float* __restrict__ R,
                           float* __restrict__ h0, int n) {
    int tid = blockIdx.x * blockDim.x + threadIdx.x;
    if (tid >= n * DIM) return;
    int nd  = tid >> 7;
    int idx = tid & 127;
    int b = idx >> 4, c = (idx >> 2) & 3, e = idx & 3;
    int base = nd * DIM + b * 16;
    float4 r = *(const float4*)&R[base + c * 4];   // R[n][b][c][0..3] contiguous
    float acc = r.x * x[base + 0 + e] + r.y * x[base + 4 + e]
              + r.z * x[base + 8 + e] + r.w * x[base + 12 + e];
    h0[tid] = acc;
}

// scatter: hdst[dst[e]] += hsrc[src[e]] * coef[e]   (32 lanes per edge, float4 each)
__global__ void scatter_kernel(const float* __restrict__ hsrc, const int* __restrict__ src,
                               const int* __restrict__ dst, const float* __restrict__ coef,
                               float* __restrict__ hdst, int nE) {
    long long tid = (long long)blockIdx.x * blockDim.x + threadIdx.x;
    long long total = (long long)nE * 32;
    if (tid >= total) return;
    int e = (int)(tid >> 5);
    int c = (int)(tid & 31);
    int s = src[e], d = dst[e];
    float cf = coef[e];
    float4 v = *(const float4*)&hsrc[(long long)s * DIM + c * 4];
    float* o = &hdst[(long long)d * DIM + c * 4];
    atomicAdd(o + 0, v.x * cf);
    atomicAdd(o + 1, v.y * cf);
    atomicAdd(o + 2, v.z * cf);
    atomicAdd(o + 3, v.w * cf);
}

// weight transposes for coalesced GEMM B-reads
__global__ void transpose_w1(const float* __restrict__ w1, float* __restrict__ w1t) {
    int tid = blockIdx.x * blockDim.x + threadIdx.x;   // 32768
    int j = tid & 255, d = tid >> 8;                   // w1 [256][128] -> w1t[128][256]
    w1t[d * 256 + j] = w1[j * 128 + d];
}
__global__ void transpose_w2(const float* __restrict__ w2, float* __restrict__ w2t) {
    int tid = blockIdx.x * blockDim.x + threadIdx.x;   // 32768
    int k = tid & 127, j = tid >> 7;                   // w2 [128][256] -> w2t[256][128]
    w2t[j * 128 + k] = w2[k * 256 + j];
}

// ---------------------------------------------------------------------------
// Fused: inverse rotation + FFN (gelu(g@w1^T+b1)@w2^T+b2) for 64 nodes/block.
// LDS: g_s [k=128][node=64] 32KB | hid_s [j=256][node=64] 64KB (phase0 scratch)
//      w_s 32KB staging. Total 128KB -> 1 block/CU, 4 waves.
__global__ __launch_bounds__(256) void ffn_kernel(
        const float* __restrict__ h,    // hA [N,128] (post scatter round 2)
        const float* __restrict__ R,    // node_rep [N,128]
        const float* __restrict__ w1t,  // [128][256]
        const float* __restrict__ b1,   // [256]
        const float* __restrict__ w2t,  // [256][128]
        const float* __restrict__ b2,   // [128]
        float* __restrict__ out, int n) {
    __shared__ float g_s[128 * 64];
    __shared__ float hid_s[256 * 64];
    __shared__ float w_s[32 * 256];
    const int tid = threadIdx.x;
    const int node0 = blockIdx.x * 64;

    // ---- phase 0: load h + R rows, inverse-rotate into g_s ([k][node] layout)
    float* h_s = hid_s;            // [64][128]
    float* R_s = hid_s + 64 * 128; // [64][128]
    for (int i = tid; i < 64 * 128 / 4; i += 256) {
        int nd = i >> 5;
        int off = (i & 31) * 4;
        int gn = node0 + nd;
        float4 hv = make_float4(0.f, 0.f, 0.f, 0.f);
        float4 rv = make_float4(0.f, 0.f, 0.f, 0.f);
        if (gn < n) {
            hv = *(const float4*)&h[(long long)gn * DIM + off];
            rv = *(const float4*)&R[(long long)gn * DIM + off];
        }
        *(float4*)&h_s[nd * 128 + off] = hv;
        *(float4*)&R_s[nd * 128 + off] = rv;
    }
    __syncthreads();
    // g[b,c,e] = sum_d R[b,d,c] * h[b,d,e]  (transposed rotation)
    for (int i = tid; i < 64 * 128; i += 256) {
        int nd = i >> 7;
        int idx = i & 127;
        int b = idx >> 4, c = (idx >> 2) & 3, e = idx & 3;
        int base = nd * 128 + b * 16;
        float acc = 0.f;
#pragma unroll
        for (int d = 0; d < 4; ++d)
            acc += R_s[base + d * 4 + c] * h_s[base + d * 4 + e];
        g_s[idx * 64 + nd] = acc;
    }
    __syncthreads();

    // ---- phase 1: hid[j][node] = gelu(g @ w1t + b1)
    const int tn = tid & 15;   // 4 nodes: tn*4..+3
    const int tj = tid >> 4;   // 16 j's:  tj*16..+15
    float acc[4][16];
#pragma unroll
    for (int a = 0; a < 4; ++a)
#pragma unroll
        for (int q = 0; q < 16; ++q) acc[a][q] = 0.f;

    for (int kc = 0; kc < 4; ++kc) {
        for (int i = tid; i < 32 * 256 / 4; i += 256) {
            int row = i >> 6;
            int col = (i & 63) * 4;
            *(float4*)&w_s[row * 256 + col] = *(const float4*)&w1t[(kc * 32 + row) * 256 + col];
        }
        __syncthreads();
        for (int kk = 0; kk < 32; ++kk) {
            int k = kc * 32 + kk;
            float4 a4 = *(const float4*)&g_s[k * 64 + tn * 4];
            float4 bq[4];
#pragma unroll
            for (int q = 0; q < 4; ++q)
                bq[q] = *(const float4*)&w_s[kk * 256 + tj * 16 + q * 4];
#pragma unroll
            for (int a = 0; a < 4; ++a) {
                float av = (&a4.x)[a];
#pragma unroll
                for (int q = 0; q < 4; ++q) {
                    acc[a][q * 4 + 0] += av * bq[q].x;
                    acc[a][q * 4 + 1] += av * bq[q].y;
                    acc[a][q * 4 + 2] += av * bq[q].z;
                    acc[a][q * 4 + 3] += av * bq[q].w;
                }
            }
        }
        __syncthreads();
    }
    // bias + exact gelu, store transposed to hid_s[j][node]
#pragma unroll
    for (int a = 0; a < 4; ++a) {
        int nd = tn * 4 + a;
#pragma unroll
        for (int q = 0; q < 16; ++q) {
            int j = tj * 16 + q;
            float v = acc[a][q] + b1[j];
            v = 0.5f * v * (1.f + erff(v * 0.70710678118654752f));
            hid_s[j * 64 + nd] = v;
        }
    }
    __syncthreads();

    // ---- phase 2: out[node][k] = hid @ w2t + b2
    const int tk = tid >> 4;   // 8 outs: tk*8..+7
    float acc2[4][8];
#pragma unroll
    for (int a = 0; a < 4; ++a)
#pragma unroll
        for (int q = 0; q < 8; ++q) acc2[a][q] = 0.f;

    for (int jc = 0; jc < 4; ++jc) {
        for (int i = tid; i < 64 * 128 / 4; i += 256) {
            int row = i >> 5;
            int col = (i & 31) * 4;
            *(float4*)&w_s[row * 128 + col] = *(const float4*)&w2t[(jc * 64 + row) * 128 + col];
        }
        __syncthreads();
        for (int jj = 0; jj < 64; ++jj) {
            int j = jc * 64 + jj;
            float4 a4 = *(const float4*)&hid_s[j * 64 + tn * 4];
            float4 b0 = *(const float4*)&w_s[jj * 128 + tk * 8];
            float4 b1v = *(const float4*)&w_s[jj * 128 + tk * 8 + 4];
#pragma unroll
            for (int a = 0; a < 4; ++a) {
                float av = (&a4.x)[a];
                acc2[a][0] += av * b0.x;
                acc2[a][1] += av * b0.y;
                acc2[a][2] += av * b0.z;
                acc2[a][3] += av * b0.w;
                acc2[a][4] += av * b1v.x;
                acc2[a][5] += av * b1v.y;
                acc2[a][6] += av * b1v.z;
                acc2[a][7] += av * b1v.w;
            }
        }
        __syncthreads();
    }
    // epilogue
    float4 bias0 = *(const float4*)&b2[tk * 8];
    float4 bias1 = *(const float4*)&b2[tk * 8 + 4];
#pragma unroll
    for (int a = 0; a < 4; ++a) {
        int gn = node0 + tn * 4 + a;
        if (gn < n) {
            float4 o0 = make_float4(acc2[a][0] + bias0.x, acc2[a][1] + bias0.y,
                                    acc2[a][2] + bias0.z, acc2[a][3] + bias0.w);
            float4 o1 = make_float4(acc2[a][4] + bias1.x, acc2[a][5] + bias1.y,
                                    acc2[a][6] + bias1.z, acc2[a][7] + bias1.w);
            *(float4*)&out[(long long)gn * DIM + tk * 8] = o0;
            *(float4*)&out[(long long)gn * DIM + tk * 8 + 4] = o1;
        }
    }
}

// ---------------------------------------------------------------------------
extern "C" void kernel_launch(void* const* d_in, const int* in_sizes, int n_in,
                              void* d_out, int out_size, void* d_ws, size_t ws_size,
                              hipStream_t stream) {
    const float* x   = (const float*)d_in[0];
    const float* R   = (const float*)d_in[1];
    const int*   src = (const int*)d_in[2];
    const int*   dst = (const int*)d_in[3];
    const float* w1  = (const float*)d_in[4];
    const float* b1  = (const float*)d_in[5];
    const float* w2  = (const float*)d_in[6];
    const float* b2  = (const float*)d_in[7];
    float* out = (float*)d_out;

    const int N = in_sizes[0] / DIM;   // 100000
    const int E = in_sizes[2];         // 1600000

    // ws layout (floats): hA [N*128] | deg [N] | coef [E] | w1t [32768] | w2t [32768]
    float* ws   = (float*)d_ws;
    float* hA   = ws;
    float* deg  = hA + (size_t)N * DIM;
    float* coef = deg + N;
    float* w1t  = coef + E;
    float* w2t  = w1t + 128 * 256;

    const int BLK = 256;

    // 1) degrees + norm coefs
    hipMemsetAsync(deg, 0, (size_t)N * sizeof(float), stream);
    deg_kernel<<<(E + BLK - 1) / BLK, BLK, 0, stream>>>(src, deg, E);
    coef_kernel<<<(E + BLK - 1) / BLK, BLK, 0, stream>>>(src, dst, deg, coef, E);

    // 2) forward rotation into hA
    rot_kernel<<<((size_t)N * DIM + BLK - 1) / BLK, BLK, 0, stream>>>(x, R, hA, N);

    // 3) scatter round 1: out <- sum hA[src]*coef
    hipMemsetAsync(out, 0, (size_t)N * DIM * sizeof(float), stream);
    {
        long long tot = (long long)E * 32;
        scatter_kernel<<<(unsigned)((tot + BLK - 1) / BLK), BLK, 0, stream>>>(hA, src, dst, coef, out, E);
    }
    // 4) scatter round 2: hA <- sum out[src]*coef
    hipMemsetAsync(hA, 0, (size_t)N * DIM * sizeof(float), stream);
    {
        long long tot = (long long)E * 32;
        scatter_kernel<<<(unsigned)((tot + BLK - 1) / BLK), BLK, 0, stream>>>(out, src, dst, coef, hA, E);
    }

    // 5) weight transposes
    transpose_w1<<<(256 * 128) / BLK, BLK, 0, stream>>>(w1, w1t);
    transpose_w2<<<(128 * 256) / BLK, BLK, 0, stream>>>(w2, w2t);

    // 6) fused inverse rotation + FFN -> out (fully overwritten)
    ffn_kernel<<<(N + 63) / 64, BLK, 0, stream>>>(hA, R, w1t, b1, w2t, b2, out, N);
}

// Round 2
// 1016.089 us; speedup vs baseline: 5.8775x; 5.8775x over previous
//
#include <hip/hip_runtime.h>
#include <hip/hip_bf16.h>
#include <math.h>

#define DIM 128
#define HID 256

// ---------------------------------------------------------------------------
// degrees: out-degree (float, for coef) + in-degree histogram (int, for CSR)
__global__ void deg_kernel(const int* __restrict__ src, const int* __restrict__ dst,
                           float* __restrict__ deg, int* __restrict__ indeg, int nE) {
    int e = blockIdx.x * blockDim.x + threadIdx.x;
    if (e < nE) {
        atomicAdd(&deg[src[e]], 1.0f);
        atomicAdd(&indeg[dst[e]], 1);
    }
}

// ---------------------------------------------------------------------------
// exclusive scan of indeg[n] -> rowstart (3-kernel hierarchical scan, 1024/block)
__global__ void scan_blocks(const int* __restrict__ in, int* __restrict__ out,
                            int* __restrict__ bsums, int n) {
    __shared__ int part[256];
    const int tid = threadIdx.x;
    const int base = blockIdx.x * 1024 + tid * 4;
    int v[4];
    int sum = 0;
#pragma unroll
    for (int k = 0; k < 4; ++k) {
        v[k] = (base + k < n) ? in[base + k] : 0;
        sum += v[k];
    }
    part[tid] = sum;
    __syncthreads();
    for (int off = 1; off < 256; off <<= 1) {
        int t = (tid >= off) ? part[tid - off] : 0;
        __syncthreads();
        part[tid] += t;
        __syncthreads();
    }
    int excl = part[tid] - sum;
    if (tid == 255) bsums[blockIdx.x] = part[255];
#pragma unroll
    for (int k = 0; k < 4; ++k) {
        if (base + k < n) out[base + k] = excl;
        excl += v[k];
    }
}

__global__ void scan_sums(int* __restrict__ bsums, int nb) {
    __shared__ int s[128];
    const int tid = threadIdx.x;
    int v = (tid < nb) ? bsums[tid] : 0;
    s[tid] = v;
    __syncthreads();
    for (int off = 1; off < 128; off <<= 1) {
        int t = (tid >= off) ? s[tid - off] : 0;
        __syncthreads();
        s[tid] += t;
        __syncthreads();
    }
    if (tid < nb) bsums[tid] = s[tid] - v;   // exclusive
}

__global__ void scan_add(int* __restrict__ rowstart, int* __restrict__ cursor,
                         const int* __restrict__ bsums, int n, int E) {
    int i = blockIdx.x * blockDim.x + threadIdx.x;
    if (i < n) {
        int v = rowstart[i] + bsums[i >> 10];
        rowstart[i] = v;
        cursor[i] = v;
    }
    if (i == n) rowstart[n] = E;
}

// permute edges into CSR-by-dst order; compute norm coef on the fly
__global__ void fill_csr(const int* __restrict__ src, const int* __restrict__ dst,
                         const float* __restrict__ deg, int* __restrict__ cursor,
                         int* __restrict__ esrc, float* __restrict__ ecoef, int nE) {
    int e = blockIdx.x * blockDim.x + threadIdx.x;
    if (e >= nE) return;
    int s = src[e], d = dst[e];
    float cf = rsqrtf(deg[s] * deg[d]);
    int pos = atomicAdd(&cursor[d], 1);
    esrc[pos] = s;
    ecoef[pos] = cf;
}

// ---------------------------------------------------------------------------
// forward rotation: h0[n,b,c,e] = sum_d R[n,b,c,d] * x[n,b,d,e]
__global__ void rot_kernel(const float* __restrict__ x, const float* __restrict__ R,
                           float* __restrict__ h0, int n) {
    int tid = blockIdx.x * blockDim.x + threadIdx.x;
    if (tid >= n * DIM) return;
    int nd  = tid >> 7;
    int idx = tid & 127;
    int b = idx >> 4, c = (idx >> 2) & 3, e = idx & 3;
    int base = nd * DIM + b * 16;
    float4 r = *(const float4*)&R[base + c * 4];
    float acc = r.x * x[base + 0 + e] + r.y * x[base + 4 + e]
              + r.z * x[base + 8 + e] + r.w * x[base + 12 + e];
    h0[tid] = acc;
}

// ---------------------------------------------------------------------------
// gather round: hdst[v] = sum_{e in CSR row v} hsrc[esrc[e]] * ecoef[e]
// one wave per node, lane owns a float2 of the 128-float row
__global__ __launch_bounds__(256) void gather_kernel(
        const float* __restrict__ hsrc, const int* __restrict__ esrc,
        const float* __restrict__ ecoef, const int* __restrict__ rowstart,
        float* __restrict__ hdst, int n) {
    int node = blockIdx.x * 4 + (threadIdx.x >> 6);
    int lane = threadIdx.x & 63;
    if (node >= n) return;
    int beg = rowstart[node];
    int end = rowstart[node + 1];
    float2 acc = make_float2(0.f, 0.f);
    int i = beg;
    for (; i + 2 <= end; i += 2) {
        int s0 = esrc[i], s1 = esrc[i + 1];
        float c0 = ecoef[i], c1 = ecoef[i + 1];
        float2 v0 = *(const float2*)&hsrc[(size_t)s0 * DIM + lane * 2];
        float2 v1 = *(const float2*)&hsrc[(size_t)s1 * DIM + lane * 2];
        acc.x += v0.x * c0 + v1.x * c1;
        acc.y += v0.y * c0 + v1.y * c1;
    }
    if (i < end) {
        int s0 = esrc[i];
        float c0 = ecoef[i];
        float2 v0 = *(const float2*)&hsrc[(size_t)s0 * DIM + lane * 2];
        acc.x += v0.x * c0;
        acc.y += v0.y * c0;
    }
    *(float2*)&hdst[(size_t)node * DIM + lane * 2] = acc;
}

// ---------------------------------------------------------------------------
// weight transposes for coalesced GEMM B-reads
__global__ void transpose_w1(const float* __restrict__ w1, float* __restrict__ w1t) {
    int tid = blockIdx.x * blockDim.x + threadIdx.x;   // 32768
    int j = tid & 255, d = tid >> 8;                   // w1 [256][128] -> w1t[128][256]
    w1t[d * 256 + j] = w1[j * 128 + d];
}
__global__ void transpose_w2(const float* __restrict__ w2, float* __restrict__ w2t) {
    int tid = blockIdx.x * blockDim.x + threadIdx.x;   // 32768
    int k = tid & 127, j = tid >> 7;                   // w2 [128][256] -> w2t[256][128]
    w2t[j * 128 + k] = w2[k * 256 + j];
}

// ---------------------------------------------------------------------------
// Fused: inverse rotation + FFN (gelu(g@w1^T+b1)@w2^T+b2) for 64 nodes/block.
__global__ __launch_bounds__(256) void ffn_kernel(
        const float* __restrict__ h,    // hA [N,128] (post scatter round 2)
        const float* __restrict__ R,    // node_rep [N,128]
        const float* __restrict__ w1t,  // [128][256]
        const float* __restrict__ b1,   // [256]
        const float* __restrict__ w2t,  // [256][128]
        const float* __restrict__ b2,   // [128]
        float* __restrict__ out, int n) {
    __shared__ float g_s[128 * 64];
    __shared__ float hid_s[256 * 64];
    __shared__ float w_s[32 * 256];
    const int tid = threadIdx.x;
    const int node0 = blockIdx.x * 64;

    // ---- phase 0: load h + R rows, inverse-rotate into g_s ([k][node] layout)
    float* h_s = hid_s;            // [64][128]
    float* R_s = hid_s + 64 * 128; // [64][128]
    for (int i = tid; i < 64 * 128 / 4; i += 256) {
        int nd = i >> 5;
        int off = (i & 31) * 4;
        int gn = node0 + nd;
        float4 hv = make_float4(0.f, 0.f, 0.f, 0.f);
        float4 rv = make_float4(0.f, 0.f, 0.f, 0.f);
        if (gn < n) {
            hv = *(const float4*)&h[(long long)gn * DIM + off];
            rv = *(const float4*)&R[(long long)gn * DIM + off];
        }
        *(float4*)&h_s[nd * 128 + off] = hv;
        *(float4*)&R_s[nd * 128 + off] = rv;
    }
    __syncthreads();
    // g[b,c,e] = sum_d R[b,d,c] * h[b,d,e]  (transposed rotation)
    for (int i = tid; i < 64 * 128; i += 256) {
        int nd = i >> 7;
        int idx = i & 127;
        int b = idx >> 4, c = (idx >> 2) & 3, e = idx & 3;
        int base = nd * 128 + b * 16;
        float acc = 0.f;
#pragma unroll
        for (int d = 0; d < 4; ++d)
            acc += R_s[base + d * 4 + c] * h_s[base + d * 4 + e];
        g_s[idx * 64 + nd] = acc;
    }
    __syncthreads();

    // ---- phase 1: hid[j][node] = gelu(g @ w1t + b1)
    const int tn = tid & 15;   // 4 nodes: tn*4..+3
    const int tj = tid >> 4;   // 16 j's:  tj*16..+15
    float acc[4][16];
#pragma unroll
    for (int a = 0; a < 4; ++a)
#pragma unroll
        for (int q = 0; q < 16; ++q) acc[a][q] = 0.f;

    for (int kc = 0; kc < 4; ++kc) {
        for (int i = tid; i < 32 * 256 / 4; i += 256) {
            int row = i >> 6;
            int col = (i & 63) * 4;
            *(float4*)&w_s[row * 256 + col] = *(const float4*)&w1t[(kc * 32 + row) * 256 + col];
        }
        __syncthreads();
        for (int kk = 0; kk < 32; ++kk) {
            int k = kc * 32 + kk;
            float4 a4 = *(const float4*)&g_s[k * 64 + tn * 4];
            float4 bq[4];
#pragma unroll
            for (int q = 0; q < 4; ++q)
                bq[q] = *(const float4*)&w_s[kk * 256 + tj * 16 + q * 4];
#pragma unroll
            for (int a = 0; a < 4; ++a) {
                float av = (&a4.x)[a];
#pragma unroll
                for (int q = 0; q < 4; ++q) {
                    acc[a][q * 4 + 0] += av * bq[q].x;
                    acc[a][q * 4 + 1] += av * bq[q].y;
                    acc[a][q * 4 + 2] += av * bq[q].z;
                    acc[a][q * 4 + 3] += av * bq[q].w;
                }
            }
        }
        __syncthreads();
    }
    // bias + exact gelu, store transposed to hid_s[j][node]
#pragma unroll
    for (int a = 0; a < 4; ++a) {
        int nd = tn * 4 + a;
#pragma unroll
        for (int q = 0; q < 16; ++q) {
            int j = tj * 16 + q;
            float v = acc[a][q] + b1[j];
            v = 0.5f * v * (1.f + erff(v * 0.70710678118654752f));
            hid_s[j * 64 + nd] = v;
        }
    }
    __syncthreads();

    // ---- phase 2: out[node][k] = hid @ w2t + b2
    const int tk = tid >> 4;   // 8 outs: tk*8..+7
    float acc2[4][8];
#pragma unroll
    for (int a = 0; a < 4; ++a)
#pragma unroll
        for (int q = 0; q < 8; ++q) acc2[a][q] = 0.f;

    for (int jc = 0; jc < 4; ++jc) {
        for (int i = tid; i < 64 * 128 / 4; i += 256) {
            int row = i >> 5;
            int col = (i & 31) * 4;
            *(float4*)&w_s[row * 128 + col] = *(const float4*)&w2t[(jc * 64 + row) * 128 + col];
        }
        __syncthreads();
        for (int jj = 0; jj < 64; ++jj) {
            int j = jc * 64 + jj;
            float4 a4 = *(const float4*)&hid_s[j * 64 + tn * 4];
            float4 b0 = *(const float4*)&w_s[jj * 128 + tk * 8];
            float4 b1v = *(const float4*)&w_s[jj * 128 + tk * 8 + 4];
#pragma unroll
            for (int a = 0; a < 4; ++a) {
                float av = (&a4.x)[a];
                acc2[a][0] += av * b0.x;
                acc2[a][1] += av * b0.y;
                acc2[a][2] += av * b0.z;
                acc2[a][3] += av * b0.w;
                acc2[a][4] += av * b1v.x;
                acc2[a][5] += av * b1v.y;
                acc2[a][6] += av * b1v.z;
                acc2[a][7] += av * b1v.w;
            }
        }
        __syncthreads();
    }
    // epilogue
    float4 bias0 = *(const float4*)&b2[tk * 8];
    float4 bias1 = *(const float4*)&b2[tk * 8 + 4];
#pragma unroll
    for (int a = 0; a < 4; ++a) {
        int gn = node0 + tn * 4 + a;
        if (gn < n) {
            float4 o0 = make_float4(acc2[a][0] + bias0.x, acc2[a][1] + bias0.y,
                                    acc2[a][2] + bias0.z, acc2[a][3] + bias0.w);
            float4 o1 = make_float4(acc2[a][4] + bias1.x, acc2[a][5] + bias1.y,
                                    acc2[a][6] + bias1.z, acc2[a][7] + bias1.w);
            *(float4*)&out[(long long)gn * DIM + tk * 8] = o0;
            *(float4*)&out[(long long)gn * DIM + tk * 8 + 4] = o1;
        }
    }
}

// ---------------------------------------------------------------------------
extern "C" void kernel_launch(void* const* d_in, const int* in_sizes, int n_in,
                              void* d_out, int out_size, void* d_ws, size_t ws_size,
                              hipStream_t stream) {
    const float* x   = (const float*)d_in[0];
    const float* R   = (const float*)d_in[1];
    const int*   src = (const int*)d_in[2];
    const int*   dst = (const int*)d_in[3];
    const float* w1  = (const float*)d_in[4];
    const float* b1  = (const float*)d_in[5];
    const float* w2  = (const float*)d_in[6];
    const float* b2  = (const float*)d_in[7];
    float* out = (float*)d_out;

    const int N = in_sizes[0] / DIM;   // 100000
    const int E = in_sizes[2];         // 1600000

    // ws layout (4-byte elems):
    // hA [N*128] | deg [N] | indeg [N] | rowstart [N+1] | cursor [N] |
    // esrc [E] | ecoef [E] | bsums [128] | w1t [32768] | w2t [32768]
    float* ws    = (float*)d_ws;
    float* hA    = ws;
    float* deg   = hA + (size_t)N * DIM;
    int*   indeg = (int*)(deg + N);
    int*   rowstart = indeg + N;
    int*   cursor   = rowstart + (N + 1);
    int*   esrc     = cursor + N;
    float* ecoef    = (float*)(esrc + E);
    int*   bsums    = (int*)(ecoef + E);
    float* w1t      = (float*)(bsums + 128);
    float* w2t      = w1t + 128 * 256;

    const int BLK = 256;

    // 1) degrees (out-deg float + in-deg histogram)
    hipMemsetAsync(deg, 0, (size_t)N * sizeof(float), stream);
    hipMemsetAsync(indeg, 0, (size_t)N * sizeof(int), stream);
    deg_kernel<<<(E + BLK - 1) / BLK, BLK, 0, stream>>>(src, dst, deg, indeg, E);

    // 2) CSR build: scan + permute
    const int nb = (N + 1023) / 1024;
    scan_blocks<<<nb, 256, 0, stream>>>(indeg, rowstart, bsums, N);
    scan_sums<<<1, 128, 0, stream>>>(bsums, nb);
    scan_add<<<(N + 1 + BLK - 1) / BLK, BLK, 0, stream>>>(rowstart, cursor, bsums, N, E);
    fill_csr<<<(E + BLK - 1) / BLK, BLK, 0, stream>>>(src, dst, deg, cursor, esrc, ecoef, E);

    // 3) forward rotation into hA
    rot_kernel<<<((size_t)N * DIM + BLK - 1) / BLK, BLK, 0, stream>>>(x, R, hA, N);

    // 4) propagation rounds as gathers (no atomics, no memset needed)
    gather_kernel<<<(N + 3) / 4, BLK, 0, stream>>>(hA, esrc, ecoef, rowstart, out, N);
    gather_kernel<<<(N + 3) / 4, BLK, 0, stream>>>(out, esrc, ecoef, rowstart, hA, N);

    // 5) weight transposes
    transpose_w1<<<(256 * 128) / BLK, BLK, 0, stream>>>(w1, w1t);
    transpose_w2<<<(128 * 256) / BLK, BLK, 0, stream>>>(w2, w2t);

    // 6) fused inverse rotation + FFN -> out (fully overwritten)
    ffn_kernel<<<(N + 63) / 64, BLK, 0, stream>>>(hA, R, w1t, b1, w2t, b2, out, N);
}

// Round 3
// 738.426 us; speedup vs baseline: 8.0876x; 1.3760x over previous
//
#include <hip/hip_runtime.h>
#include <hip/hip_bf16.h>
#include <math.h>

#define DIM 128
#define HID 256

typedef short s8x __attribute__((ext_vector_type(8)));   // 8 bf16 (as raw shorts)
typedef float f4x __attribute__((ext_vector_type(4)));   // MFMA accumulator

__device__ __forceinline__ unsigned short f2bf(float f) {
    unsigned int u = __float_as_uint(f);
    u += 0x7FFF + ((u >> 16) & 1);   // round-to-nearest-even
    return (unsigned short)(u >> 16);
}

// ---------------------------------------------------------------------------
// degrees: out-degree (float, for coef) + in-degree histogram (int, for CSR)
__global__ void deg_kernel(const int* __restrict__ src, const int* __restrict__ dst,
                           float* __restrict__ deg, int* __restrict__ indeg, int nE) {
    int e = blockIdx.x * blockDim.x + threadIdx.x;
    if (e < nE) {
        atomicAdd(&deg[src[e]], 1.0f);
        atomicAdd(&indeg[dst[e]], 1);
    }
}

// ---------------------------------------------------------------------------
// exclusive scan of indeg[n] -> rowstart (3-kernel hierarchical scan, 1024/block)
__global__ void scan_blocks(const int* __restrict__ in, int* __restrict__ out,
                            int* __restrict__ bsums, int n) {
    __shared__ int part[256];
    const int tid = threadIdx.x;
    const int base = blockIdx.x * 1024 + tid * 4;
    int v[4];
    int sum = 0;
#pragma unroll
    for (int k = 0; k < 4; ++k) {
        v[k] = (base + k < n) ? in[base + k] : 0;
        sum += v[k];
    }
    part[tid] = sum;
    __syncthreads();
    for (int off = 1; off < 256; off <<= 1) {
        int t = (tid >= off) ? part[tid - off] : 0;
        __syncthreads();
        part[tid] += t;
        __syncthreads();
    }
    int excl = part[tid] - sum;
    if (tid == 255) bsums[blockIdx.x] = part[255];
#pragma unroll
    for (int k = 0; k < 4; ++k) {
        if (base + k < n) out[base + k] = excl;
        excl += v[k];
    }
}

__global__ void scan_sums(int* __restrict__ bsums, int nb) {
    __shared__ int s[128];
    const int tid = threadIdx.x;
    int v = (tid < nb) ? bsums[tid] : 0;
    s[tid] = v;
    __syncthreads();
    for (int off = 1; off < 128; off <<= 1) {
        int t = (tid >= off) ? s[tid - off] : 0;
        __syncthreads();
        s[tid] += t;
        __syncthreads();
    }
    if (tid < nb) bsums[tid] = s[tid] - v;   // exclusive
}

__global__ void scan_add(int* __restrict__ rowstart, int* __restrict__ cursor,
                         const int* __restrict__ bsums, int n, int E) {
    int i = blockIdx.x * blockDim.x + threadIdx.x;
    if (i < n) {
        int v = rowstart[i] + bsums[i >> 10];
        rowstart[i] = v;
        cursor[i] = v;
    }
    if (i == n) rowstart[n] = E;
}

// permute edges into CSR-by-dst order; compute norm coef on the fly
__global__ void fill_csr(const int* __restrict__ src, const int* __restrict__ dst,
                         const float* __restrict__ deg, int* __restrict__ cursor,
                         int* __restrict__ esrc, float* __restrict__ ecoef, int nE) {
    int e = blockIdx.x * blockDim.x + threadIdx.x;
    if (e >= nE) return;
    int s = src[e], d = dst[e];
    float cf = rsqrtf(deg[s] * deg[d]);
    int pos = atomicAdd(&cursor[d], 1);
    esrc[pos] = s;
    ecoef[pos] = cf;
}

// ---------------------------------------------------------------------------
// forward rotation: h0[n,b,c,e] = sum_d R[n,b,c,d] * x[n,b,d,e]
__global__ void rot_kernel(const float* __restrict__ x, const float* __restrict__ R,
                           float* __restrict__ h0, int n) {
    int tid = blockIdx.x * blockDim.x + threadIdx.x;
    if (tid >= n * DIM) return;
    int nd  = tid >> 7;
    int idx = tid & 127;
    int b = idx >> 4, c = (idx >> 2) & 3, e = idx & 3;
    int base = nd * DIM + b * 16;
    float4 r = *(const float4*)&R[base + c * 4];
    float acc = r.x * x[base + 0 + e] + r.y * x[base + 4 + e]
              + r.z * x[base + 8 + e] + r.w * x[base + 12 + e];
    h0[tid] = acc;
}

// ---------------------------------------------------------------------------
// gather round: hdst[v] = sum_{e in CSR row v} hsrc[esrc[e]] * ecoef[e]
__global__ __launch_bounds__(256) void gather_kernel(
        const float* __restrict__ hsrc, const int* __restrict__ esrc,
        const float* __restrict__ ecoef, const int* __restrict__ rowstart,
        float* __restrict__ hdst, int n) {
    int node = blockIdx.x * 4 + (threadIdx.x >> 6);
    int lane = threadIdx.x & 63;
    if (node >= n) return;
    int beg = rowstart[node];
    int end = rowstart[node + 1];
    float2 acc = make_float2(0.f, 0.f);
    int i = beg;
    for (; i + 2 <= end; i += 2) {
        int s0 = esrc[i], s1 = esrc[i + 1];
        float c0 = ecoef[i], c1 = ecoef[i + 1];
        float2 v0 = *(const float2*)&hsrc[(size_t)s0 * DIM + lane * 2];
        float2 v1 = *(const float2*)&hsrc[(size_t)s1 * DIM + lane * 2];
        acc.x += v0.x * c0 + v1.x * c1;
        acc.y += v0.y * c0 + v1.y * c1;
    }
    if (i < end) {
        int s0 = esrc[i];
        float c0 = ecoef[i];
        float2 v0 = *(const float2*)&hsrc[(size_t)s0 * DIM + lane * 2];
        acc.x += v0.x * c0;
        acc.y += v0.y * c0;
    }
    *(float2*)&hdst[(size_t)node * DIM + lane * 2] = acc;
}

// ---------------------------------------------------------------------------
// weights fp32 -> bf16 (bit pattern in ushort), layouts unchanged:
// w1 [256][128] row-major == B[n][k] for GEMM1; w2 [128][256] == B[n][k] for GEMM2
__global__ void cvt_weights(const float* __restrict__ w1, const float* __restrict__ w2,
                            unsigned short* __restrict__ w1b, unsigned short* __restrict__ w2b) {
    int t = blockIdx.x * blockDim.x + threadIdx.x;   // 32768 threads
    w1b[t] = f2bf(w1[t]);
    w2b[t] = f2bf(w2[t]);
}

// ---------------------------------------------------------------------------
// Fused inverse-rotation + FFN via bf16 MFMA. 64 nodes/block, 256 threads.
// LDS: abuf [64][136] bf16 (A for GEMM1, padded), hbuf [64][264] bf16 (A for GEMM2).
// B fragments come straight from global bf16 weights (L1/L2-resident, already in
// MFMA B [n][k] layout). fp32 accumulate, exact GELU on fp32.
#define ABST 136
#define HBST 264
__global__ __launch_bounds__(256, 3) void ffn_kernel(
        const float* __restrict__ h,    // hA [N,128] (post 2nd gather)
        const float* __restrict__ R,    // node_rep [N,128]
        const unsigned short* __restrict__ w1b,  // [256][128] bf16
        const float* __restrict__ b1,            // [256]
        const unsigned short* __restrict__ w2b,  // [128][256] bf16
        const float* __restrict__ b2,            // [128]
        float* __restrict__ out, int n) {
    __shared__ unsigned short abuf[64 * ABST];
    __shared__ unsigned short hbuf[64 * HBST];
    const int tid  = threadIdx.x;
    const int node0 = blockIdx.x * 64;
    const int wave = tid >> 6;
    const int lane = tid & 63;
    const int lr = lane & 15;   // tile row (A) / tile col (B,C)
    const int lq = lane >> 4;   // quad -> k-block / C row group

    // ---- phase 0: inverse rotation g = R^T-rot(h), straight to bf16 A-layout
    for (int u = tid; u < 512; u += 256) {     // (node,bundle) units
        int nd = u >> 3, b = u & 7;
        int gn = node0 + nd;
        float hv[16], rv[16];
        if (gn < n) {
            const float* hp = &h[(size_t)gn * DIM + b * 16];
            const float* Rp = &R[(size_t)gn * DIM + b * 16];
#pragma unroll
            for (int d = 0; d < 4; ++d) {
                *(float4*)&hv[d * 4] = *(const float4*)&hp[d * 4];
                *(float4*)&rv[d * 4] = *(const float4*)&Rp[d * 4];
            }
        } else {
#pragma unroll
            for (int d = 0; d < 16; ++d) { hv[d] = 0.f; rv[d] = 0.f; }
        }
        // g[c][e] = sum_d R[b][d][c] * h[b][d][e]
#pragma unroll
        for (int c = 0; c < 4; ++c) {
            unsigned short gb[4];
#pragma unroll
            for (int e = 0; e < 4; ++e) {
                float acc = 0.f;
#pragma unroll
                for (int d = 0; d < 4; ++d) acc += rv[d * 4 + c] * hv[d * 4 + e];
                gb[e] = f2bf(acc);
            }
            *(ushort4*)&abuf[nd * ABST + b * 16 + c * 4] =
                make_ushort4(gb[0], gb[1], gb[2], gb[3]);
        }
    }
    __syncthreads();

    // ---- GEMM1: hid[64][256] = gelu(A[64,128] @ w1^T + b1), wave owns 64 cols
    f4x acc1[4][4];
#pragma unroll
    for (int mt = 0; mt < 4; ++mt)
#pragma unroll
        for (int nt = 0; nt < 4; ++nt) acc1[mt][nt] = (f4x){0.f, 0.f, 0.f, 0.f};

    const int nw = wave * 64;
    for (int ks = 0; ks < 4; ++ks) {
        const int k0 = ks * 32 + lq * 8;
        s8x af[4], bf[4];
#pragma unroll
        for (int mt = 0; mt < 4; ++mt)
            af[mt] = *(const s8x*)&abuf[(mt * 16 + lr) * ABST + k0];
#pragma unroll
        for (int nt = 0; nt < 4; ++nt)
            bf[nt] = *(const s8x*)&w1b[(size_t)(nw + nt * 16 + lr) * 128 + k0];
#pragma unroll
        for (int mt = 0; mt < 4; ++mt)
#pragma unroll
            for (int nt = 0; nt < 4; ++nt)
                acc1[mt][nt] = __builtin_amdgcn_mfma_f32_16x16x32_bf16(
                    af[mt], bf[nt], acc1[mt][nt], 0, 0, 0);
    }
    // epilogue: bias + exact gelu -> bf16 hbuf[m][n]
#pragma unroll
    for (int nt = 0; nt < 4; ++nt) {
        int nn = nw + nt * 16 + lr;
        float bias = b1[nn];
#pragma unroll
        for (int mt = 0; mt < 4; ++mt) {
#pragma unroll
            for (int r = 0; r < 4; ++r) {
                float v = acc1[mt][nt][r] + bias;
                v = 0.5f * v * (1.f + erff(v * 0.70710678118654752f));
                hbuf[(mt * 16 + lq * 4 + r) * HBST + nn] = f2bf(v);
            }
        }
    }
    __syncthreads();

    // ---- GEMM2: out[64][128] = hid[64,256] @ w2^T + b2, wave owns 32 cols
    f4x acc2[4][2];
#pragma unroll
    for (int mt = 0; mt < 4; ++mt)
#pragma unroll
        for (int nt = 0; nt < 2; ++nt) acc2[mt][nt] = (f4x){0.f, 0.f, 0.f, 0.f};

    const int nw2 = wave * 32;
    for (int ks = 0; ks < 8; ++ks) {
        const int k0 = ks * 32 + lq * 8;
        s8x af[4], bf2[2];
#pragma unroll
        for (int mt = 0; mt < 4; ++mt)
            af[mt] = *(const s8x*)&hbuf[(mt * 16 + lr) * HBST + k0];
#pragma unroll
        for (int nt = 0; nt < 2; ++nt)
            bf2[nt] = *(const s8x*)&w2b[(size_t)(nw2 + nt * 16 + lr) * 256 + k0];
#pragma unroll
        for (int mt = 0; mt < 4; ++mt)
#pragma unroll
            for (int nt = 0; nt < 2; ++nt)
                acc2[mt][nt] = __builtin_amdgcn_mfma_f32_16x16x32_bf16(
                    af[mt], bf2[nt], acc2[mt][nt], 0, 0, 0);
    }
    // epilogue: bias + store fp32
#pragma unroll
    for (int nt = 0; nt < 2; ++nt) {
        int n2 = nw2 + nt * 16 + lr;
        float bias = b2[n2];
#pragma unroll
        for (int mt = 0; mt < 4; ++mt) {
#pragma unroll
            for (int r = 0; r < 4; ++r) {
                int gn = node0 + mt * 16 + lq * 4 + r;
                if (gn < n) out[(size_t)gn * DIM + n2] = acc2[mt][nt][r] + bias;
            }
        }
    }
}

// ---------------------------------------------------------------------------
extern "C" void kernel_launch(void* const* d_in, const int* in_sizes, int n_in,
                              void* d_out, int out_size, void* d_ws, size_t ws_size,
                              hipStream_t stream) {
    const float* x   = (const float*)d_in[0];
    const float* R   = (const float*)d_in[1];
    const int*   src = (const int*)d_in[2];
    const int*   dst = (const int*)d_in[3];
    const float* w1  = (const float*)d_in[4];
    const float* b1  = (const float*)d_in[5];
    const float* w2  = (const float*)d_in[6];
    const float* b2  = (const float*)d_in[7];
    float* out = (float*)d_out;

    const int N = in_sizes[0] / DIM;   // 100000
    const int E = in_sizes[2];         // 1600000

    // ws layout (4-byte elems):
    // hA [N*128] | deg [N] | indeg [N] | rowstart [N+1] | cursor [N] |
    // esrc [E] | ecoef [E] | bsums [128] | (align 64B) w1b [32768 us] | w2b [32768 us]
    float* ws    = (float*)d_ws;
    float* hA    = ws;
    float* deg   = hA + (size_t)N * DIM;
    int*   indeg = (int*)(deg + N);
    int*   rowstart = indeg + N;
    int*   cursor   = rowstart + (N + 1);
    int*   esrc     = cursor + N;
    float* ecoef    = (float*)(esrc + E);
    int*   bsums    = (int*)(ecoef + E);
    uintptr_t wp = ((uintptr_t)(bsums + 128) + 63) & ~(uintptr_t)63;
    unsigned short* w1b = (unsigned short*)wp;
    unsigned short* w2b = w1b + 32768;

    const int BLK = 256;

    // 1) degrees (out-deg float + in-deg histogram)
    hipMemsetAsync(deg, 0, (size_t)N * sizeof(float), stream);
    hipMemsetAsync(indeg, 0, (size_t)N * sizeof(int), stream);
    deg_kernel<<<(E + BLK - 1) / BLK, BLK, 0, stream>>>(src, dst, deg, indeg, E);

    // 2) CSR build: scan + permute
    const int nb = (N + 1023) / 1024;
    scan_blocks<<<nb, 256, 0, stream>>>(indeg, rowstart, bsums, N);
    scan_sums<<<1, 128, 0, stream>>>(bsums, nb);
    scan_add<<<(N + 1 + BLK - 1) / BLK, BLK, 0, stream>>>(rowstart, cursor, bsums, N, E);
    fill_csr<<<(E + BLK - 1) / BLK, BLK, 0, stream>>>(src, dst, deg, cursor, esrc, ecoef, E);

    // 3) forward rotation into hA; weights -> bf16
    rot_kernel<<<((size_t)N * DIM + BLK - 1) / BLK, BLK, 0, stream>>>(x, R, hA, N);
    cvt_weights<<<32768 / BLK, BLK, 0, stream>>>(w1, w2, w1b, w2b);

    // 4) propagation rounds as gathers (no atomics)
    gather_kernel<<<(N + 3) / 4, BLK, 0, stream>>>(hA, esrc, ecoef, rowstart, out, N);
    gather_kernel<<<(N + 3) / 4, BLK, 0, stream>>>(out, esrc, ecoef, rowstart, hA, N);

    // 5) fused inverse rotation + FFN (bf16 MFMA) -> out
    ffn_kernel<<<(N + 63) / 64, BLK, 0, stream>>>(hA, R, w1b, b1, w2b, b2, out, N);
}

// Round 4
// 693.040 us; speedup vs baseline: 8.6173x; 1.0655x over previous
//
#include <hip/hip_runtime.h>
#include <hip/hip_bf16.h>
#include <math.h>

#define DIM 128
#define HID 256

typedef short s8x __attribute__((ext_vector_type(8)));   // 8 bf16 (as raw shorts)
typedef float f4x __attribute__((ext_vector_type(4)));   // MFMA accumulator

__device__ __forceinline__ unsigned short f2bf(float f) {
    unsigned int u = __float_as_uint(f);
    u += 0x7FFF + ((u >> 16) & 1);   // round-to-nearest-even
    return (unsigned short)(u >> 16);
}
__device__ __forceinline__ float bf2f(unsigned short b) {
    return __uint_as_float(((unsigned int)b) << 16);
}

// ---------------------------------------------------------------------------
// degrees: out-degree (float, for coef) + in-degree histogram (int, for CSR)
__global__ void deg_kernel(const int* __restrict__ src, const int* __restrict__ dst,
                           float* __restrict__ deg, int* __restrict__ indeg, int nE) {
    int e = blockIdx.x * blockDim.x + threadIdx.x;
    if (e < nE) {
        atomicAdd(&deg[src[e]], 1.0f);
        atomicAdd(&indeg[dst[e]], 1);
    }
}

// ---------------------------------------------------------------------------
// exclusive scan of indeg[n] -> rowstart (3-kernel hierarchical scan, 1024/block)
__global__ void scan_blocks(const int* __restrict__ in, int* __restrict__ out,
                            int* __restrict__ bsums, int n) {
    __shared__ int part[256];
    const int tid = threadIdx.x;
    const int base = blockIdx.x * 1024 + tid * 4;
    int v[4];
    int sum = 0;
#pragma unroll
    for (int k = 0; k < 4; ++k) {
        v[k] = (base + k < n) ? in[base + k] : 0;
        sum += v[k];
    }
    part[tid] = sum;
    __syncthreads();
    for (int off = 1; off < 256; off <<= 1) {
        int t = (tid >= off) ? part[tid - off] : 0;
        __syncthreads();
        part[tid] += t;
        __syncthreads();
    }
    int excl = part[tid] - sum;
    if (tid == 255) bsums[blockIdx.x] = part[255];
#pragma unroll
    for (int k = 0; k < 4; ++k) {
        if (base + k < n) out[base + k] = excl;
        excl += v[k];
    }
}

__global__ void scan_sums(int* __restrict__ bsums, int nb) {
    __shared__ int s[128];
    const int tid = threadIdx.x;
    int v = (tid < nb) ? bsums[tid] : 0;
    s[tid] = v;
    __syncthreads();
    for (int off = 1; off < 128; off <<= 1) {
        int t = (tid >= off) ? s[tid - off] : 0;
        __syncthreads();
        s[tid] += t;
        __syncthreads();
    }
    if (tid < nb) bsums[tid] = s[tid] - v;   // exclusive
}

__global__ void scan_add(int* __restrict__ rowstart, int* __restrict__ cursor,
                         const int* __restrict__ bsums, int n, int E) {
    int i = blockIdx.x * blockDim.x + threadIdx.x;
    if (i < n) {
        int v = rowstart[i] + bsums[i >> 10];
        rowstart[i] = v;
        cursor[i] = v;
    }
    if (i == n) rowstart[n] = E;
}

// permute edges into CSR-by-dst order (src index only; coef recomputed in gather)
__global__ void fill_csr(const int* __restrict__ src, const int* __restrict__ dst,
                         int* __restrict__ cursor, int* __restrict__ esrc, int nE) {
    int e = blockIdx.x * blockDim.x + threadIdx.x;
    if (e >= nE) return;
    int pos = atomicAdd(&cursor[dst[e]], 1);
    esrc[pos] = src[e];
}

// ---------------------------------------------------------------------------
// forward rotation -> bf16 rows: h0[n,b,c,e] = sum_d R[n,b,c,d] * x[n,b,d,e]
// one thread per (node,bundle): reads 2x64B, writes 32B bf16
__global__ void rot_kernel(const float* __restrict__ x, const float* __restrict__ R,
                           unsigned short* __restrict__ h0, int n) {
    int u = blockIdx.x * blockDim.x + threadIdx.x;
    if (u >= n * 8) return;
    int nd = u >> 3, b = u & 7;
    const float* xp = &x[(size_t)nd * DIM + b * 16];
    const float* Rp = &R[(size_t)nd * DIM + b * 16];
    float xv[16], rv[16];
#pragma unroll
    for (int d = 0; d < 4; ++d) {
        *(float4*)&xv[d * 4] = *(const float4*)&xp[d * 4];
        *(float4*)&rv[d * 4] = *(const float4*)&Rp[d * 4];
    }
    unsigned short ob[16];
#pragma unroll
    for (int c = 0; c < 4; ++c)
#pragma unroll
        for (int e = 0; e < 4; ++e) {
            float acc = 0.f;
#pragma unroll
            for (int d = 0; d < 4; ++d) acc += rv[c * 4 + d] * xv[d * 4 + e];
            ob[c * 4 + e] = f2bf(acc);
        }
    unsigned short* op = &h0[(size_t)nd * DIM + b * 16];
    *(s8x*)&op[0] = *(s8x*)&ob[0];
    *(s8x*)&op[8] = *(s8x*)&ob[8];
}

// ---------------------------------------------------------------------------
// gather round (bf16 rows): hdst[v] = sum_{e in row v} hsrc[esrc[e]] * coef(e)
// one wave per node, lane owns 2 bf16 (4B) of the 256B row; fp32 accumulate
__global__ __launch_bounds__(256) void gather_kernel(
        const unsigned short* __restrict__ hsrc, const int* __restrict__ esrc,
        const float* __restrict__ deg, const int* __restrict__ rowstart,
        unsigned short* __restrict__ hdst, int n) {
    int node = blockIdx.x * 4 + (threadIdx.x >> 6);
    int lane = threadIdx.x & 63;
    if (node >= n) return;
    int beg = rowstart[node];
    int end = rowstart[node + 1];
    float dd = deg[node];
    float accx = 0.f, accy = 0.f;
    int i = beg;
    for (; i + 2 <= end; i += 2) {
        int s0 = esrc[i], s1 = esrc[i + 1];
        float c0 = rsqrtf(deg[s0] * dd);
        float c1 = rsqrtf(deg[s1] * dd);
        unsigned int p0 = *(const unsigned int*)&hsrc[(size_t)s0 * DIM + lane * 2];
        unsigned int p1 = *(const unsigned int*)&hsrc[(size_t)s1 * DIM + lane * 2];
        accx += bf2f((unsigned short)p0) * c0 + bf2f((unsigned short)p1) * c1;
        accy += bf2f((unsigned short)(p0 >> 16)) * c0 + bf2f((unsigned short)(p1 >> 16)) * c1;
    }
    if (i < end) {
        int s0 = esrc[i];
        float c0 = rsqrtf(deg[s0] * dd);
        unsigned int p0 = *(const unsigned int*)&hsrc[(size_t)s0 * DIM + lane * 2];
        accx += bf2f((unsigned short)p0) * c0;
        accy += bf2f((unsigned short)(p0 >> 16)) * c0;
    }
    unsigned int packed = (unsigned int)f2bf(accx) | ((unsigned int)f2bf(accy) << 16);
    *(unsigned int*)&hdst[(size_t)node * DIM + lane * 2] = packed;
}

// ---------------------------------------------------------------------------
// weights fp32 -> bf16, layouts unchanged (already MFMA B [n][k] row-major)
__global__ void cvt_weights(const float* __restrict__ w1, const float* __restrict__ w2,
                            unsigned short* __restrict__ w1b, unsigned short* __restrict__ w2b) {
    int t = blockIdx.x * blockDim.x + threadIdx.x;   // 32768 threads
    w1b[t] = f2bf(w1[t]);
    w2b[t] = f2bf(w2[t]);
}

// ---------------------------------------------------------------------------
// Fused inverse-rotation + FFN via bf16 MFMA. 64 nodes/block, 256 threads.
#define ABST 136
#define HBST 264
__global__ __launch_bounds__(256, 3) void ffn_kernel(
        const unsigned short* __restrict__ h,    // hA [N,128] bf16 (post 2nd gather)
        const float* __restrict__ R,             // node_rep [N,128] fp32
        const unsigned short* __restrict__ w1b,  // [256][128] bf16
        const float* __restrict__ b1,            // [256]
        const unsigned short* __restrict__ w2b,  // [128][256] bf16
        const float* __restrict__ b2,            // [128]
        float* __restrict__ out, int n) {
    __shared__ unsigned short abuf[64 * ABST];
    __shared__ unsigned short hbuf[64 * HBST];
    const int tid  = threadIdx.x;
    const int node0 = blockIdx.x * 64;
    const int wave = tid >> 6;
    const int lane = tid & 63;
    const int lr = lane & 15;   // tile row (A) / tile col (B,C)
    const int lq = lane >> 4;   // quad -> k-block / C row group

    // ---- phase 0: inverse rotation g = R^T-rot(h), straight to bf16 A-layout
    for (int u = tid; u < 512; u += 256) {     // (node,bundle) units
        int nd = u >> 3, b = u & 7;
        int gn = node0 + nd;
        float hv[16], rv[16];
        if (gn < n) {
            const unsigned short* hp = &h[(size_t)gn * DIM + b * 16];
            const float* Rp = &R[(size_t)gn * DIM + b * 16];
            unsigned short hraw[16];
            *(s8x*)&hraw[0] = *(const s8x*)&hp[0];
            *(s8x*)&hraw[8] = *(const s8x*)&hp[8];
#pragma unroll
            for (int d = 0; d < 16; ++d) hv[d] = bf2f(hraw[d]);
#pragma unroll
            for (int d = 0; d < 4; ++d)
                *(float4*)&rv[d * 4] = *(const float4*)&Rp[d * 4];
        } else {
#pragma unroll
            for (int d = 0; d < 16; ++d) { hv[d] = 0.f; rv[d] = 0.f; }
        }
        // g[c][e] = sum_d R[b][d][c] * h[b][d][e]
#pragma unroll
        for (int c = 0; c < 4; ++c) {
            unsigned short gb[4];
#pragma unroll
            for (int e = 0; e < 4; ++e) {
                float acc = 0.f;
#pragma unroll
                for (int d = 0; d < 4; ++d) acc += rv[d * 4 + c] * hv[d * 4 + e];
                gb[e] = f2bf(acc);
            }
            *(ushort4*)&abuf[nd * ABST + b * 16 + c * 4] =
                make_ushort4(gb[0], gb[1], gb[2], gb[3]);
        }
    }
    __syncthreads();

    // ---- GEMM1: hid[64][256] = gelu(A[64,128] @ w1^T + b1), wave owns 64 cols
    f4x acc1[4][4];
#pragma unroll
    for (int mt = 0; mt < 4; ++mt)
#pragma unroll
        for (int nt = 0; nt < 4; ++nt) acc1[mt][nt] = (f4x){0.f, 0.f, 0.f, 0.f};

    const int nw = wave * 64;
    for (int ks = 0; ks < 4; ++ks) {
        const int k0 = ks * 32 + lq * 8;
        s8x af[4], bf[4];
#pragma unroll
        for (int mt = 0; mt < 4; ++mt)
            af[mt] = *(const s8x*)&abuf[(mt * 16 + lr) * ABST + k0];
#pragma unroll
        for (int nt = 0; nt < 4; ++nt)
            bf[nt] = *(const s8x*)&w1b[(size_t)(nw + nt * 16 + lr) * 128 + k0];
#pragma unroll
        for (int mt = 0; mt < 4; ++mt)
#pragma unroll
            for (int nt = 0; nt < 4; ++nt)
                acc1[mt][nt] = __builtin_amdgcn_mfma_f32_16x16x32_bf16(
                    af[mt], bf[nt], acc1[mt][nt], 0, 0, 0);
    }
    // epilogue: bias + exact gelu -> bf16 hbuf[m][n]
#pragma unroll
    for (int nt = 0; nt < 4; ++nt) {
        int nn = nw + nt * 16 + lr;
        float bias = b1[nn];
#pragma unroll
        for (int mt = 0; mt < 4; ++mt) {
#pragma unroll
            for (int r = 0; r < 4; ++r) {
                float v = acc1[mt][nt][r] + bias;
                v = 0.5f * v * (1.f + erff(v * 0.70710678118654752f));
                hbuf[(mt * 16 + lq * 4 + r) * HBST + nn] = f2bf(v);
            }
        }
    }
    __syncthreads();

    // ---- GEMM2: out[64][128] = hid[64,256] @ w2^T + b2, wave owns 32 cols
    f4x acc2[4][2];
#pragma unroll
    for (int mt = 0; mt < 4; ++mt)
#pragma unroll
        for (int nt = 0; nt < 2; ++nt) acc2[mt][nt] = (f4x){0.f, 0.f, 0.f, 0.f};

    const int nw2 = wave * 32;
    for (int ks = 0; ks < 8; ++ks) {
        const int k0 = ks * 32 + lq * 8;
        s8x af[4], bf2v[2];
#pragma unroll
        for (int mt = 0; mt < 4; ++mt)
            af[mt] = *(const s8x*)&hbuf[(mt * 16 + lr) * HBST + k0];
#pragma unroll
        for (int nt = 0; nt < 2; ++nt)
            bf2v[nt] = *(const s8x*)&w2b[(size_t)(nw2 + nt * 16 + lr) * 256 + k0];
#pragma unroll
        for (int mt = 0; mt < 4; ++mt)
#pragma unroll
            for (int nt = 0; nt < 2; ++nt)
                acc2[mt][nt] = __builtin_amdgcn_mfma_f32_16x16x32_bf16(
                    af[mt], bf2v[nt], acc2[mt][nt], 0, 0, 0);
    }
    // epilogue: bias + store fp32
#pragma unroll
    for (int nt = 0; nt < 2; ++nt) {
        int n2 = nw2 + nt * 16 + lr;
        float bias = b2[n2];
#pragma unroll
        for (int mt = 0; mt < 4; ++mt) {
#pragma unroll
            for (int r = 0; r < 4; ++r) {
                int gn = node0 + mt * 16 + lq * 4 + r;
                if (gn < n) out[(size_t)gn * DIM + n2] = acc2[mt][nt][r] + bias;
            }
        }
    }
}

// ---------------------------------------------------------------------------
extern "C" void kernel_launch(void* const* d_in, const int* in_sizes, int n_in,
                              void* d_out, int out_size, void* d_ws, size_t ws_size,
                              hipStream_t stream) {
    const float* x   = (const float*)d_in[0];
    const float* R   = (const float*)d_in[1];
    const int*   src = (const int*)d_in[2];
    const int*   dst = (const int*)d_in[3];
    const float* w1  = (const float*)d_in[4];
    const float* b1  = (const float*)d_in[5];
    const float* w2  = (const float*)d_in[6];
    const float* b2  = (const float*)d_in[7];
    float* out = (float*)d_out;

    const int N = in_sizes[0] / DIM;   // 100000
    const int E = in_sizes[2];         // 1600000

    // ws layout:
    // hA [N*128 ushort] | hM [N*128 ushort] | deg [N f32] | indeg [N] |
    // rowstart [N+1] | cursor [N] | esrc [E] | bsums [128] | w1b | w2b
    unsigned short* hA = (unsigned short*)d_ws;
    unsigned short* hM = hA + (size_t)N * DIM;
    float* deg      = (float*)(hM + (size_t)N * DIM);
    int*   indeg    = (int*)(deg + N);
    int*   rowstart = indeg + N;
    int*   cursor   = rowstart + (N + 1);
    int*   esrc     = cursor + N;
    int*   bsums    = esrc + E;
    unsigned short* w1b = (unsigned short*)(bsums + 128);
    unsigned short* w2b = w1b + 32768;

    const int BLK = 256;

    // 1) degrees (out-deg float + in-deg histogram)
    hipMemsetAsync(deg, 0, (size_t)N * sizeof(float), stream);
    hipMemsetAsync(indeg, 0, (size_t)N * sizeof(int), stream);
    deg_kernel<<<(E + BLK - 1) / BLK, BLK, 0, stream>>>(src, dst, deg, indeg, E);

    // 2) CSR build: scan + permute (src only)
    const int nb = (N + 1023) / 1024;
    scan_blocks<<<nb, 256, 0, stream>>>(indeg, rowstart, bsums, N);
    scan_sums<<<1, 128, 0, stream>>>(bsums, nb);
    scan_add<<<(N + 1 + BLK - 1) / BLK, BLK, 0, stream>>>(rowstart, cursor, bsums, N, E);
    fill_csr<<<(E + BLK - 1) / BLK, BLK, 0, stream>>>(src, dst, cursor, esrc, E);

    // 3) forward rotation into hA (bf16); weights -> bf16
    rot_kernel<<<((size_t)N * 8 + BLK - 1) / BLK, BLK, 0, stream>>>(x, R, hA, N);
    cvt_weights<<<32768 / BLK, BLK, 0, stream>>>(w1, w2, w1b, w2b);

    // 4) propagation rounds as gathers (bf16 rows, coef on the fly)
    gather_kernel<<<(N + 3) / 4, BLK, 0, stream>>>(hA, esrc, deg, rowstart, hM, N);
    gather_kernel<<<(N + 3) / 4, BLK, 0, stream>>>(hM, esrc, deg, rowstart, hA, N);

    // 5) fused inverse rotation + FFN (bf16 MFMA) -> out
    ffn_kernel<<<(N + 63) / 64, BLK, 0, stream>>>(hA, R, w1b, b1, w2b, b2, out, N);
}

// Round 5
// 518.033 us; speedup vs baseline: 11.5284x; 1.3378x over previous
//
#include <hip/hip_runtime.h>
#include <hip/hip_bf16.h>
#include <math.h>

#define DIM 128
#define HID 256

typedef short s8x __attribute__((ext_vector_type(8)));   // 8 bf16 (as raw shorts)
typedef float f4x __attribute__((ext_vector_type(4)));   // MFMA accumulator

__device__ __forceinline__ unsigned short f2bf(float f) {
    unsigned int u = __float_as_uint(f);
    u += 0x7FFF + ((u >> 16) & 1);   // round-to-nearest-even
    return (unsigned short)(u >> 16);
}
__device__ __forceinline__ float bf2f(unsigned short b) {
    return __uint_as_float(((unsigned int)b) << 16);
}

// ===========================================================================
// CSR build via bucketed counting sort (no device-scope atomics).
// Buckets: node id >> 7 (128 nodes/bucket), nbuck = ceil(N/128) <= 1024.
// ===========================================================================

// pass 1: per-(block,bucket) histograms of dst (for CSR) and src (for out-deg)
__global__ __launch_bounds__(256) void hist_kernel(
        const int* __restrict__ src, const int* __restrict__ dst,
        int* __restrict__ TD, int* __restrict__ TS, int nE, int nbuck, int chunk) {
    __shared__ int hd[1024], hs[1024];
    const int tid = threadIdx.x, blk = blockIdx.x;
    for (int b = tid; b < nbuck; b += 256) { hd[b] = 0; hs[b] = 0; }
    __syncthreads();
    int beg = blk * chunk, end = min(beg + chunk, nE);
    for (int i = beg + tid; i < end; i += 256) {
        atomicAdd(&hd[dst[i] >> 7], 1);
        atomicAdd(&hs[src[i] >> 7], 1);
    }
    __syncthreads();
    for (int b = tid; b < nbuck; b += 256) {   // bucket-major layout for scan
        TD[b * 256 + blk] = hd[b];
        TS[b * 256 + blk] = hs[b];
    }
}

// hierarchical exclusive scan (in-place capable): 1024 elems/block
__global__ void scan_blocks(const int* in, int* out, int* bsums, int n) {
    __shared__ int part[256];
    const int tid = threadIdx.x;
    const int base = blockIdx.x * 1024 + tid * 4;
    int v[4];
    int sum = 0;
#pragma unroll
    for (int k = 0; k < 4; ++k) {
        v[k] = (base + k < n) ? in[base + k] : 0;
        sum += v[k];
    }
    part[tid] = sum;
    __syncthreads();
    for (int off = 1; off < 256; off <<= 1) {
        int t = (tid >= off) ? part[tid - off] : 0;
        __syncthreads();
        part[tid] += t;
        __syncthreads();
    }
    int excl = part[tid] - sum;
    if (tid == 255) bsums[blockIdx.x] = part[255];
#pragma unroll
    for (int k = 0; k < 4; ++k) {
        if (base + k < n) out[base + k] = excl;
        excl += v[k];
    }
}

__global__ void scan_sums(int* bsums, int nb) {
    __shared__ int s[256];
    const int tid = threadIdx.x;
    int v = (tid < nb) ? bsums[tid] : 0;
    s[tid] = v;
    __syncthreads();
    for (int off = 1; off < 256; off <<= 1) {
        int t = (tid >= off) ? s[tid - off] : 0;
        __syncthreads();
        s[tid] += t;
        __syncthreads();
    }
    if (tid < nb) bsums[tid] = s[tid] - v;   // exclusive
}

__global__ void scan_add(int* T, const int* __restrict__ bsums, int n) {
    int i = blockIdx.x * blockDim.x + threadIdx.x;
    if (i < n) T[i] += bsums[i >> 10];
}

// pass 2: scatter edges into bucket-ordered arrays using LDS cursors
__global__ __launch_bounds__(256) void scatter_edges(
        const int* __restrict__ src, const int* __restrict__ dst,
        const int* __restrict__ TD, const int* __restrict__ TS,
        unsigned long long* __restrict__ pairs, int* __restrict__ srcval,
        int nE, int nbuck, int chunk) {
    __shared__ int cd[1024], cs[1024];
    const int tid = threadIdx.x, blk = blockIdx.x;
    for (int b = tid; b < nbuck; b += 256) {
        cd[b] = TD[b * 256 + blk];
        cs[b] = TS[b * 256 + blk];
    }
    __syncthreads();
    int beg = blk * chunk, end = min(beg + chunk, nE);
    for (int i = beg + tid; i < end; i += 256) {
        int s = src[i], d = dst[i];
        int pd = atomicAdd(&cd[d >> 7], 1);
        pairs[pd] = ((unsigned long long)(unsigned)s << 32) | (unsigned)d;
        int ps = atomicAdd(&cs[s >> 7], 1);
        srcval[ps] = s;
    }
}

// pass 3: per-bucket CSR finalize: rowstart + locally sorted esrc
__global__ __launch_bounds__(256) void csr_finalize(
        const unsigned long long* __restrict__ pairs, const int* __restrict__ TD,
        int* __restrict__ rowstart, int* __restrict__ esrc, int nE, int nbuck, int nN) {
    __shared__ int hist[128], sbuf[128], cur[128];
    const int tid = threadIdx.x, b = blockIdx.x;
    int beg = TD[b * 256];
    int end = (b + 1 < nbuck) ? TD[(b + 1) * 256] : nE;
    if (tid < 128) hist[tid] = 0;
    __syncthreads();
    for (int i = beg + tid; i < end; i += 256)
        atomicAdd(&hist[(int)((unsigned)pairs[i] & 127u)], 1);
    __syncthreads();
    int v = (tid < 128) ? hist[tid] : 0;
    if (tid < 128) sbuf[tid] = v;
    __syncthreads();
    for (int off = 1; off < 128; off <<= 1) {
        int t = (tid < 128 && tid >= off) ? sbuf[tid - off] : 0;
        __syncthreads();
        if (tid < 128) sbuf[tid] += t;
        __syncthreads();
    }
    if (tid < 128) {
        int excl = sbuf[tid] - v;
        cur[tid] = excl;
        int idx = (b << 7) + tid;
        if (idx <= nN) rowstart[idx] = beg + excl;   // covers rowstart[N]=E too
    }
    __syncthreads();
    for (int i = beg + tid; i < end; i += 256) {
        unsigned long long p = pairs[i];
        int l = (int)((unsigned)p & 127u);
        int s = (int)(p >> 32);
        int pos = atomicAdd(&cur[l], 1);
        esrc[beg + pos] = s;
    }
}

// pass 4: per-bucket out-degree from bucket-sorted src values
__global__ __launch_bounds__(256) void deg_finalize(
        const int* __restrict__ srcval, const int* __restrict__ TS,
        float* __restrict__ deg, int nE, int nbuck, int nN) {
    __shared__ int hist[128];
    const int tid = threadIdx.x, b = blockIdx.x;
    int beg = TS[b * 256];
    int end = (b + 1 < nbuck) ? TS[(b + 1) * 256] : nE;
    if (tid < 128) hist[tid] = 0;
    __syncthreads();
    for (int i = beg + tid; i < end; i += 256)
        atomicAdd(&hist[srcval[i] & 127], 1);
    __syncthreads();
    if (tid < 128) {
        int idx = (b << 7) + tid;
        if (idx < nN) deg[idx] = (float)hist[tid];
    }
}

// ---------------------------------------------------------------------------
// forward rotation -> bf16 rows: h0[n,b,c,e] = sum_d R[n,b,c,d] * x[n,b,d,e]
__global__ void rot_kernel(const float* __restrict__ x, const float* __restrict__ R,
                           unsigned short* __restrict__ h0, int n) {
    int u = blockIdx.x * blockDim.x + threadIdx.x;
    if (u >= n * 8) return;
    int nd = u >> 3, b = u & 7;
    const float* xp = &x[(size_t)nd * DIM + b * 16];
    const float* Rp = &R[(size_t)nd * DIM + b * 16];
    float xv[16], rv[16];
#pragma unroll
    for (int d = 0; d < 4; ++d) {
        *(float4*)&xv[d * 4] = *(const float4*)&xp[d * 4];
        *(float4*)&rv[d * 4] = *(const float4*)&Rp[d * 4];
    }
    unsigned short ob[16];
#pragma unroll
    for (int c = 0; c < 4; ++c)
#pragma unroll
        for (int e = 0; e < 4; ++e) {
            float acc = 0.f;
#pragma unroll
            for (int d = 0; d < 4; ++d) acc += rv[c * 4 + d] * xv[d * 4 + e];
            ob[c * 4 + e] = f2bf(acc);
        }
    unsigned short* op = &h0[(size_t)nd * DIM + b * 16];
    *(s8x*)&op[0] = *(s8x*)&ob[0];
    *(s8x*)&op[8] = *(s8x*)&ob[8];
}

// ---------------------------------------------------------------------------
// gather round (bf16 rows): hdst[v] = sum_{e in row v} hsrc[esrc[e]] * coef(e)
__global__ __launch_bounds__(256) void gather_kernel(
        const unsigned short* __restrict__ hsrc, const int* __restrict__ esrc,
        const float* __restrict__ deg, const int* __restrict__ rowstart,
        unsigned short* __restrict__ hdst, int n) {
    int node = blockIdx.x * 4 + (threadIdx.x >> 6);
    int lane = threadIdx.x & 63;
    if (node >= n) return;
    int beg = rowstart[node];
    int end = rowstart[node + 1];
    float dd = deg[node];
    float accx = 0.f, accy = 0.f;
    int i = beg;
    for (; i + 2 <= end; i += 2) {
        int s0 = esrc[i], s1 = esrc[i + 1];
        float c0 = rsqrtf(deg[s0] * dd);
        float c1 = rsqrtf(deg[s1] * dd);
        unsigned int p0 = *(const unsigned int*)&hsrc[(size_t)s0 * DIM + lane * 2];
        unsigned int p1 = *(const unsigned int*)&hsrc[(size_t)s1 * DIM + lane * 2];
        accx += bf2f((unsigned short)p0) * c0 + bf2f((unsigned short)p1) * c1;
        accy += bf2f((unsigned short)(p0 >> 16)) * c0 + bf2f((unsigned short)(p1 >> 16)) * c1;
    }
    if (i < end) {
        int s0 = esrc[i];
        float c0 = rsqrtf(deg[s0] * dd);
        unsigned int p0 = *(const unsigned int*)&hsrc[(size_t)s0 * DIM + lane * 2];
        accx += bf2f((unsigned short)p0) * c0;
        accy += bf2f((unsigned short)(p0 >> 16)) * c0;
    }
    unsigned int packed = (unsigned int)f2bf(accx) | ((unsigned int)f2bf(accy) << 16);
    *(unsigned int*)&hdst[(size_t)node * DIM + lane * 2] = packed;
}

// ---------------------------------------------------------------------------
// weights fp32 -> bf16, layouts unchanged (already MFMA B [n][k] row-major)
__global__ void cvt_weights(const float* __restrict__ w1, const float* __restrict__ w2,
                            unsigned short* __restrict__ w1b, unsigned short* __restrict__ w2b) {
    int t = blockIdx.x * blockDim.x + threadIdx.x;   // 32768 threads
    w1b[t] = f2bf(w1[t]);
    w2b[t] = f2bf(w2[t]);
}

// ---------------------------------------------------------------------------
// Fused inverse-rotation + FFN via bf16 MFMA. 64 nodes/block, 256 threads.
#define ABST 136
#define HBST 264
__global__ __launch_bounds__(256, 3) void ffn_kernel(
        const unsigned short* __restrict__ h,    // hA [N,128] bf16 (post 2nd gather)
        const float* __restrict__ R,             // node_rep [N,128] fp32
        const unsigned short* __restrict__ w1b,  // [256][128] bf16
        const float* __restrict__ b1,            // [256]
        const unsigned short* __restrict__ w2b,  // [128][256] bf16
        const float* __restrict__ b2,            // [128]
        float* __restrict__ out, int n) {
    __shared__ unsigned short abuf[64 * ABST];
    __shared__ unsigned short hbuf[64 * HBST];
    const int tid  = threadIdx.x;
    const int node0 = blockIdx.x * 64;
    const int wave = tid >> 6;
    const int lane = tid & 63;
    const int lr = lane & 15;   // tile row (A) / tile col (B,C)
    const int lq = lane >> 4;   // quad -> k-block / C row group

    // ---- phase 0: inverse rotation g = R^T-rot(h), straight to bf16 A-layout
    for (int u = tid; u < 512; u += 256) {     // (node,bundle) units
        int nd = u >> 3, b = u & 7;
        int gn = node0 + nd;
        float hv[16], rv[16];
        if (gn < n) {
            const unsigned short* hp = &h[(size_t)gn * DIM + b * 16];
            const float* Rp = &R[(size_t)gn * DIM + b * 16];
            unsigned short hraw[16];
            *(s8x*)&hraw[0] = *(const s8x*)&hp[0];
            *(s8x*)&hraw[8] = *(const s8x*)&hp[8];
#pragma unroll
            for (int d = 0; d < 16; ++d) hv[d] = bf2f(hraw[d]);
#pragma unroll
            for (int d = 0; d < 4; ++d)
                *(float4*)&rv[d * 4] = *(const float4*)&Rp[d * 4];
        } else {
#pragma unroll
            for (int d = 0; d < 16; ++d) { hv[d] = 0.f; rv[d] = 0.f; }
        }
        // g[c][e] = sum_d R[b][d][c] * h[b][d][e]
#pragma unroll
        for (int c = 0; c < 4; ++c) {
            unsigned short gb[4];
#pragma unroll
            for (int e = 0; e < 4; ++e) {
                float acc = 0.f;
#pragma unroll
                for (int d = 0; d < 4; ++d) acc += rv[d * 4 + c] * hv[d * 4 + e];
                gb[e] = f2bf(acc);
            }
            *(ushort4*)&abuf[nd * ABST + b * 16 + c * 4] =
                make_ushort4(gb[0], gb[1], gb[2], gb[3]);
        }
    }
    __syncthreads();

    // ---- GEMM1: hid[64][256] = gelu(A[64,128] @ w1^T + b1), wave owns 64 cols
    f4x acc1[4][4];
#pragma unroll
    for (int mt = 0; mt < 4; ++mt)
#pragma unroll
        for (int nt = 0; nt < 4; ++nt) acc1[mt][nt] = (f4x){0.f, 0.f, 0.f, 0.f};

    const int nw = wave * 64;
    for (int ks = 0; ks < 4; ++ks) {
        const int k0 = ks * 32 + lq * 8;
        s8x af[4], bf[4];
#pragma unroll
        for (int mt = 0; mt < 4; ++mt)
            af[mt] = *(const s8x*)&abuf[(mt * 16 + lr) * ABST + k0];
#pragma unroll
        for (int nt = 0; nt < 4; ++nt)
            bf[nt] = *(const s8x*)&w1b[(size_t)(nw + nt * 16 + lr) * 128 + k0];
#pragma unroll
        for (int mt = 0; mt < 4; ++mt)
#pragma unroll
            for (int nt = 0; nt < 4; ++nt)
                acc1[mt][nt] = __builtin_amdgcn_mfma_f32_16x16x32_bf16(
                    af[mt], bf[nt], acc1[mt][nt], 0, 0, 0);
    }
    // epilogue: bias + exact gelu -> bf16 hbuf[m][n]
#pragma unroll
    for (int nt = 0; nt < 4; ++nt) {
        int nn = nw + nt * 16 + lr;
        float bias = b1[nn];
#pragma unroll
        for (int mt = 0; mt < 4; ++mt) {
#pragma unroll
            for (int r = 0; r < 4; ++r) {
                float v = acc1[mt][nt][r] + bias;
                v = 0.5f * v * (1.f + erff(v * 0.70710678118654752f));
                hbuf[(mt * 16 + lq * 4 + r) * HBST + nn] = f2bf(v);
            }
        }
    }
    __syncthreads();

    // ---- GEMM2: out[64][128] = hid[64,256] @ w2^T + b2, wave owns 32 cols
    f4x acc2[4][2];
#pragma unroll
    for (int mt = 0; mt < 4; ++mt)
#pragma unroll
        for (int nt = 0; nt < 2; ++nt) acc2[mt][nt] = (f4x){0.f, 0.f, 0.f, 0.f};

    const int nw2 = wave * 32;
    for (int ks = 0; ks < 8; ++ks) {
        const int k0 = ks * 32 + lq * 8;
        s8x af[4], bf2v[2];
#pragma unroll
        for (int mt = 0; mt < 4; ++mt)
            af[mt] = *(const s8x*)&hbuf[(mt * 16 + lr) * HBST + k0];
#pragma unroll
        for (int nt = 0; nt < 2; ++nt)
            bf2v[nt] = *(const s8x*)&w2b[(size_t)(nw2 + nt * 16 + lr) * 256 + k0];
#pragma unroll
        for (int mt = 0; mt < 4; ++mt)
#pragma unroll
            for (int nt = 0; nt < 2; ++nt)
                acc2[mt][nt] = __builtin_amdgcn_mfma_f32_16x16x32_bf16(
                    af[mt], bf2v[nt], acc2[mt][nt], 0, 0, 0);
    }
    // epilogue: bias + store fp32
#pragma unroll
    for (int nt = 0; nt < 2; ++nt) {
        int n2 = nw2 + nt * 16 + lr;
        float bias = b2[n2];
#pragma unroll
        for (int mt = 0; mt < 4; ++mt) {
#pragma unroll
            for (int r = 0; r < 4; ++r) {
                int gn = node0 + mt * 16 + lq * 4 + r;
                if (gn < n) out[(size_t)gn * DIM + n2] = acc2[mt][nt][r] + bias;
            }
        }
    }
}

// ---------------------------------------------------------------------------
extern "C" void kernel_launch(void* const* d_in, const int* in_sizes, int n_in,
                              void* d_out, int out_size, void* d_ws, size_t ws_size,
                              hipStream_t stream) {
    const float* x   = (const float*)d_in[0];
    const float* R   = (const float*)d_in[1];
    const int*   src = (const int*)d_in[2];
    const int*   dst = (const int*)d_in[3];
    const float* w1  = (const float*)d_in[4];
    const float* b1  = (const float*)d_in[5];
    const float* w2  = (const float*)d_in[6];
    const float* b2  = (const float*)d_in[7];
    float* out = (float*)d_out;

    const int N = in_sizes[0] / DIM;   // 100000
    const int E = in_sizes[2];         // 1600000

    const int nbuck = (N + 127) >> 7;          // 782
    const int chunk = (E + 255) / 256;         // 6250
    const int nScan = nbuck * 256;             // 200192
    const int nbScan = (nScan + 1023) / 1024;  // 196 (<=256)

    // ws layout:
    // hA [N*128 bf16] | hM [N*128 bf16]  (hM aliased by pairs[E u64] + srcval[E int])
    // deg [N f32] | rowstart [N+1] | esrc [E] | TD [nScan] | TS [nScan] |
    // bsums [256] | w1b [32768 us] | w2b [32768 us]
    unsigned short* hA = (unsigned short*)d_ws;
    unsigned short* hM = hA + (size_t)N * DIM;
    unsigned long long* pairs = (unsigned long long*)hM;     // scratch, dead before gather1
    int* srcval = (int*)(pairs + E);
    float* deg      = (float*)(hM + (size_t)N * DIM);
    int*   rowstart = (int*)(deg + N);
    int*   esrc     = rowstart + (N + 1);
    int*   TD       = esrc + E;
    int*   TS       = TD + nScan;
    int*   bsums    = TS + nScan;
    unsigned short* w1b = (unsigned short*)(bsums + 256);
    unsigned short* w2b = w1b + 32768;

    const int BLK = 256;

    // 1) CSR + degree build via bucketed counting sort (no global atomics)
    hist_kernel<<<256, BLK, 0, stream>>>(src, dst, TD, TS, E, nbuck, chunk);
    scan_blocks<<<nbScan, BLK, 0, stream>>>(TD, TD, bsums, nScan);
    scan_sums<<<1, BLK, 0, stream>>>(bsums, nbScan);
    scan_add<<<(nScan + BLK - 1) / BLK, BLK, 0, stream>>>(TD, bsums, nScan);
    scan_blocks<<<nbScan, BLK, 0, stream>>>(TS, TS, bsums, nScan);
    scan_sums<<<1, BLK, 0, stream>>>(bsums, nbScan);
    scan_add<<<(nScan + BLK - 1) / BLK, BLK, 0, stream>>>(TS, bsums, nScan);
    scatter_edges<<<256, BLK, 0, stream>>>(src, dst, TD, TS, pairs, srcval, E, nbuck, chunk);
    csr_finalize<<<nbuck, BLK, 0, stream>>>(pairs, TD, rowstart, esrc, E, nbuck, N);
    deg_finalize<<<nbuck, BLK, 0, stream>>>(srcval, TS, deg, E, nbuck, N);

    // 2) forward rotation into hA (bf16); weights -> bf16
    rot_kernel<<<((size_t)N * 8 + BLK - 1) / BLK, BLK, 0, stream>>>(x, R, hA, N);
    cvt_weights<<<32768 / BLK, BLK, 0, stream>>>(w1, w2, w1b, w2b);

    // 3) propagation rounds as gathers (bf16 rows, coef on the fly)
    gather_kernel<<<(N + 3) / 4, BLK, 0, stream>>>(hA, esrc, deg, rowstart, hM, N);
    gather_kernel<<<(N + 3) / 4, BLK, 0, stream>>>(hM, esrc, deg, rowstart, hA, N);

    // 4) fused inverse rotation + FFN (bf16 MFMA) -> out
    ffn_kernel<<<(N + 63) / 64, BLK, 0, stream>>>(hA, R, w1b, b1, w2b, b2, out, N);
}

// Round 6
// 445.944 us; speedup vs baseline: 13.3920x; 1.1617x over previous
//
#include <hip/hip_runtime.h>
#include <hip/hip_bf16.h>
#include <math.h>

#define DIM 128
#define HID 256

typedef short s8x __attribute__((ext_vector_type(8)));   // 8 bf16 (as raw shorts)
typedef float f4x __attribute__((ext_vector_type(4)));   // MFMA accumulator

__device__ __forceinline__ unsigned short f2bf(float f) {
    unsigned int u = __float_as_uint(f);
    u += 0x7FFF + ((u >> 16) & 1);   // round-to-nearest-even
    return (unsigned short)(u >> 16);
}
__device__ __forceinline__ float bf2f(unsigned short b) {
    return __uint_as_float(((unsigned int)b) << 16);
}
__device__ __forceinline__ float bflo(unsigned int p) {   // low bf16 of packed pair
    return __uint_as_float(p << 16);
}
__device__ __forceinline__ float bfhi(unsigned int p) {   // high bf16 of packed pair
    return __uint_as_float(p & 0xffff0000u);
}

// ===========================================================================
// CSR build via bucketed counting sort (no device-scope atomics).
// Buckets: node id >> 7 (128 nodes/bucket), nbuck = ceil(N/128) <= 1024.
// ===========================================================================

// pass 1: per-(block,bucket) histograms of dst (for CSR) and src (for out-deg)
__global__ __launch_bounds__(256) void hist_kernel(
        const int* __restrict__ src, const int* __restrict__ dst,
        int* __restrict__ TD, int* __restrict__ TS, int nE, int nbuck, int chunk) {
    __shared__ int hd[1024], hs[1024];
    const int tid = threadIdx.x, blk = blockIdx.x;
    for (int b = tid; b < nbuck; b += 256) { hd[b] = 0; hs[b] = 0; }
    __syncthreads();
    int beg = blk * chunk, end = min(beg + chunk, nE);
    for (int i = beg + tid; i < end; i += 256) {
        atomicAdd(&hd[dst[i] >> 7], 1);
        atomicAdd(&hs[src[i] >> 7], 1);
    }
    __syncthreads();
    for (int b = tid; b < nbuck; b += 256) {   // bucket-major layout for scan
        TD[b * 256 + blk] = hd[b];
        TS[b * 256 + blk] = hs[b];
    }
}

// hierarchical exclusive scan: 1024 elems/block
__global__ void scan_blocks(const int* in, int* out, int* bsums, int n) {
    __shared__ int part[256];
    const int tid = threadIdx.x;
    const int base = blockIdx.x * 1024 + tid * 4;
    int v[4];
    int sum = 0;
#pragma unroll
    for (int k = 0; k < 4; ++k) {
        v[k] = (base + k < n) ? in[base + k] : 0;
        sum += v[k];
    }
    part[tid] = sum;
    __syncthreads();
    for (int off = 1; off < 256; off <<= 1) {
        int t = (tid >= off) ? part[tid - off] : 0;
        __syncthreads();
        part[tid] += t;
        __syncthreads();
    }
    int excl = part[tid] - sum;
    if (tid == 255) bsums[blockIdx.x] = part[255];
#pragma unroll
    for (int k = 0; k < 4; ++k) {
        if (base + k < n) out[base + k] = excl;
        excl += v[k];
    }
}

// scan of block sums, nb <= 1024, single block of 256
__global__ void scan_sums(int* bsums, int nb) {
    __shared__ int part[256];
    const int tid = threadIdx.x;
    const int base = tid * 4;
    int v[4];
    int sum = 0;
#pragma unroll
    for (int k = 0; k < 4; ++k) {
        v[k] = (base + k < nb) ? bsums[base + k] : 0;
        sum += v[k];
    }
    part[tid] = sum;
    __syncthreads();
    for (int off = 1; off < 256; off <<= 1) {
        int t = (tid >= off) ? part[tid - off] : 0;
        __syncthreads();
        part[tid] += t;
        __syncthreads();
    }
    int excl = part[tid] - sum;
#pragma unroll
    for (int k = 0; k < 4; ++k) {
        if (base + k < nb) bsums[base + k] = excl;
        excl += v[k];
    }
}

// add block offsets; second half (TS region) additionally corrected by -E
__global__ void scan_add(int* T, const int* __restrict__ bsums, int n2, int half, int E) {
    int i = blockIdx.x * blockDim.x + threadIdx.x;
    if (i < n2) {
        int v = T[i] + bsums[i >> 10];
        T[i] = (i >= half) ? v - E : v;
    }
}

// pass 2: scatter edges into bucket-ordered arrays using LDS cursors
__global__ __launch_bounds__(256) void scatter_edges(
        const int* __restrict__ src, const int* __restrict__ dst,
        const int* __restrict__ TD, const int* __restrict__ TS,
        unsigned long long* __restrict__ pairs, int* __restrict__ srcval,
        int nE, int nbuck, int chunk) {
    __shared__ int cd[1024], cs[1024];
    const int tid = threadIdx.x, blk = blockIdx.x;
    for (int b = tid; b < nbuck; b += 256) {
        cd[b] = TD[b * 256 + blk];
        cs[b] = TS[b * 256 + blk];
    }
    __syncthreads();
    int beg = blk * chunk, end = min(beg + chunk, nE);
    for (int i = beg + tid; i < end; i += 256) {
        int s = src[i], d = dst[i];
        int pd = atomicAdd(&cd[d >> 7], 1);
        pairs[pd] = ((unsigned long long)(unsigned)s << 32) | (unsigned)d;
        int ps = atomicAdd(&cs[s >> 7], 1);
        srcval[ps] = s;
    }
}

// pass 3: per-bucket finalize: rowstart + locally sorted esrc + rdeg
__global__ __launch_bounds__(256) void finalize_kernel(
        const unsigned long long* __restrict__ pairs, const int* __restrict__ TD,
        const int* __restrict__ srcval, const int* __restrict__ TS,
        int* __restrict__ rowstart, int* __restrict__ esrc,
        float* __restrict__ rdeg, int nE, int nbuck, int nN) {
    __shared__ int hist[128], sbuf[128], cur[128];
    const int tid = threadIdx.x, b = blockIdx.x;
    // ---- CSR part (dst-bucket) ----
    int beg = TD[b * 256];
    int end = (b + 1 < nbuck) ? TD[(b + 1) * 256] : nE;
    if (tid < 128) hist[tid] = 0;
    __syncthreads();
    for (int i = beg + tid; i < end; i += 256)
        atomicAdd(&hist[(int)((unsigned)pairs[i] & 127u)], 1);
    __syncthreads();
    int v = (tid < 128) ? hist[tid] : 0;
    if (tid < 128) sbuf[tid] = v;
    __syncthreads();
    for (int off = 1; off < 128; off <<= 1) {
        int t = (tid < 128 && tid >= off) ? sbuf[tid - off] : 0;
        __syncthreads();
        if (tid < 128) sbuf[tid] += t;
        __syncthreads();
    }
    if (tid < 128) {
        int excl = sbuf[tid] - v;
        cur[tid] = excl;
        int idx = (b << 7) + tid;
        if (idx <= nN) rowstart[idx] = beg + excl;   // covers rowstart[N]=E too
    }
    __syncthreads();
    for (int i = beg + tid; i < end; i += 256) {
        unsigned long long p = pairs[i];
        int l = (int)((unsigned)p & 127u);
        int s = (int)(p >> 32);
        int pos = atomicAdd(&cur[l], 1);
        esrc[beg + pos] = s;
    }
    __syncthreads();
    // ---- out-degree part (src-bucket) -> rdeg = rsqrt(deg) ----
    if (tid < 128) hist[tid] = 0;
    __syncthreads();
    int beg2 = TS[b * 256];
    int end2 = (b + 1 < nbuck) ? TS[(b + 1) * 256] : nE;
    for (int i = beg2 + tid; i < end2; i += 256)
        atomicAdd(&hist[srcval[i] & 127], 1);
    __syncthreads();
    if (tid < 128) {
        int idx = (b << 7) + tid;
        if (idx < nN) rdeg[idx] = rsqrtf((float)hist[tid]);
    }
}

// ---------------------------------------------------------------------------
// forward rotation -> bf16 rows; tail blocks convert weights to bf16
__global__ void rot_cvt_kernel(const float* __restrict__ x, const float* __restrict__ R,
                               unsigned short* __restrict__ h0,
                               const float* __restrict__ w1, const float* __restrict__ w2,
                               unsigned short* __restrict__ w1b, unsigned short* __restrict__ w2b,
                               int n, int nbRot) {
    if ((int)blockIdx.x >= nbRot) {
        int t = (blockIdx.x - nbRot) * 256 + threadIdx.x;   // 16 blocks = 4096 threads
        for (int i = t; i < 32768; i += 4096) {
            w1b[i] = f2bf(w1[i]);
            w2b[i] = f2bf(w2[i]);
        }
        return;
    }
    int u = blockIdx.x * blockDim.x + threadIdx.x;
    if (u >= n * 8) return;
    int nd = u >> 3, b = u & 7;
    const float* xp = &x[(size_t)nd * DIM + b * 16];
    const float* Rp = &R[(size_t)nd * DIM + b * 16];
    float xv[16], rv[16];
#pragma unroll
    for (int d = 0; d < 4; ++d) {
        *(float4*)&xv[d * 4] = *(const float4*)&xp[d * 4];
        *(float4*)&rv[d * 4] = *(const float4*)&Rp[d * 4];
    }
    unsigned short ob[16];
#pragma unroll
    for (int c = 0; c < 4; ++c)
#pragma unroll
        for (int e = 0; e < 4; ++e) {
            float acc = 0.f;
#pragma unroll
            for (int d = 0; d < 4; ++d) acc += rv[c * 4 + d] * xv[d * 4 + e];
            ob[c * 4 + e] = f2bf(acc);
        }
    unsigned short* op = &h0[(size_t)nd * DIM + b * 16];
    *(s8x*)&op[0] = *(s8x*)&ob[0];
    *(s8x*)&op[8] = *(s8x*)&ob[8];
}

// ---------------------------------------------------------------------------
// gather round (bf16 rows): hdst[v] = sum_{e in row v} hsrc[esrc[e]] * coef(e)
// 32 lanes per node (8 B each), 8 nodes per 256-block; coef = rdeg[s]*rdeg[v]
__global__ __launch_bounds__(256) void gather_kernel(
        const unsigned short* __restrict__ hsrc, const int* __restrict__ esrc,
        const float* __restrict__ rdeg, const int* __restrict__ rowstart,
        unsigned short* __restrict__ hdst, int n) {
    int node = blockIdx.x * 8 + (threadIdx.x >> 5);
    int lane = threadIdx.x & 31;          // owns 4 bf16 = 8 B of the row
    if (node >= n) return;
    int beg = rowstart[node];
    int end = rowstart[node + 1];
    float rd = rdeg[node];
    float a0 = 0.f, a1 = 0.f, a2 = 0.f, a3 = 0.f;
    int i = beg;
    for (; i + 2 <= end; i += 2) {
        int s0 = esrc[i], s1 = esrc[i + 1];
        float c0 = rdeg[s0] * rd;
        float c1 = rdeg[s1] * rd;
        uint2 p0 = *(const uint2*)&hsrc[(size_t)s0 * DIM + lane * 4];
        uint2 p1 = *(const uint2*)&hsrc[(size_t)s1 * DIM + lane * 4];
        a0 += bflo(p0.x) * c0 + bflo(p1.x) * c1;
        a1 += bfhi(p0.x) * c0 + bfhi(p1.x) * c1;
        a2 += bflo(p0.y) * c0 + bflo(p1.y) * c1;
        a3 += bfhi(p0.y) * c0 + bfhi(p1.y) * c1;
    }
    if (i < end) {
        int s0 = esrc[i];
        float c0 = rdeg[s0] * rd;
        uint2 p0 = *(const uint2*)&hsrc[(size_t)s0 * DIM + lane * 4];
        a0 += bflo(p0.x) * c0;
        a1 += bfhi(p0.x) * c0;
        a2 += bflo(p0.y) * c0;
        a3 += bfhi(p0.y) * c0;
    }
    uint2 packed;
    packed.x = (unsigned int)f2bf(a0) | ((unsigned int)f2bf(a1) << 16);
    packed.y = (unsigned int)f2bf(a2) | ((unsigned int)f2bf(a3) << 16);
    *(uint2*)&hdst[(size_t)node * DIM + lane * 4] = packed;
}

// ---------------------------------------------------------------------------
// Fused inverse-rotation + FFN via bf16 MFMA. 64 nodes/block, 256 threads.
#define ABST 136
#define HBST 264
__global__ __launch_bounds__(256, 3) void ffn_kernel(
        const unsigned short* __restrict__ h,    // hA [N,128] bf16 (post 2nd gather)
        const float* __restrict__ R,             // node_rep [N,128] fp32
        const unsigned short* __restrict__ w1b,  // [256][128] bf16
        const float* __restrict__ b1,            // [256]
        const unsigned short* __restrict__ w2b,  // [128][256] bf16
        const float* __restrict__ b2,            // [128]
        float* __restrict__ out, int n) {
    __shared__ unsigned short abuf[64 * ABST];
    __shared__ unsigned short hbuf[64 * HBST];
    const int tid  = threadIdx.x;
    const int node0 = blockIdx.x * 64;
    const int wave = tid >> 6;
    const int lane = tid & 63;
    const int lr = lane & 15;   // tile row (A) / tile col (B,C)
    const int lq = lane >> 4;   // quad -> k-block / C row group

    // ---- phase 0: inverse rotation g = R^T-rot(h), straight to bf16 A-layout
    for (int u = tid; u < 512; u += 256) {     // (node,bundle) units
        int nd = u >> 3, b = u & 7;
        int gn = node0 + nd;
        float hv[16], rv[16];
        if (gn < n) {
            const unsigned short* hp = &h[(size_t)gn * DIM + b * 16];
            const float* Rp = &R[(size_t)gn * DIM + b * 16];
            unsigned short hraw[16];
            *(s8x*)&hraw[0] = *(const s8x*)&hp[0];
            *(s8x*)&hraw[8] = *(const s8x*)&hp[8];
#pragma unroll
            for (int d = 0; d < 16; ++d) hv[d] = bf2f(hraw[d]);
#pragma unroll
            for (int d = 0; d < 4; ++d)
                *(float4*)&rv[d * 4] = *(const float4*)&Rp[d * 4];
        } else {
#pragma unroll
            for (int d = 0; d < 16; ++d) { hv[d] = 0.f; rv[d] = 0.f; }
        }
        // g[c][e] = sum_d R[b][d][c] * h[b][d][e]
#pragma unroll
        for (int c = 0; c < 4; ++c) {
            unsigned short gb[4];
#pragma unroll
            for (int e = 0; e < 4; ++e) {
                float acc = 0.f;
#pragma unroll
                for (int d = 0; d < 4; ++d) acc += rv[d * 4 + c] * hv[d * 4 + e];
                gb[e] = f2bf(acc);
            }
            *(ushort4*)&abuf[nd * ABST + b * 16 + c * 4] =
                make_ushort4(gb[0], gb[1], gb[2], gb[3]);
        }
    }
    __syncthreads();

    // ---- GEMM1: hid[64][256] = gelu(A[64,128] @ w1^T + b1), wave owns 64 cols
    f4x acc1[4][4];
#pragma unroll
    for (int mt = 0; mt < 4; ++mt)
#pragma unroll
        for (int nt = 0; nt < 4; ++nt) acc1[mt][nt] = (f4x){0.f, 0.f, 0.f, 0.f};

    const int nw = wave * 64;
    for (int ks = 0; ks < 4; ++ks) {
        const int k0 = ks * 32 + lq * 8;
        s8x af[4], bf[4];
#pragma unroll
        for (int mt = 0; mt < 4; ++mt)
            af[mt] = *(const s8x*)&abuf[(mt * 16 + lr) * ABST + k0];
#pragma unroll
        for (int nt = 0; nt < 4; ++nt)
            bf[nt] = *(const s8x*)&w1b[(size_t)(nw + nt * 16 + lr) * 128 + k0];
#pragma unroll
        for (int mt = 0; mt < 4; ++mt)
#pragma unroll
            for (int nt = 0; nt < 4; ++nt)
                acc1[mt][nt] = __builtin_amdgcn_mfma_f32_16x16x32_bf16(
                    af[mt], bf[nt], acc1[mt][nt], 0, 0, 0);
    }
    // epilogue: bias + exact gelu -> bf16 hbuf[m][n]
#pragma unroll
    for (int nt = 0; nt < 4; ++nt) {
        int nn = nw + nt * 16 + lr;
        float bias = b1[nn];
#pragma unroll
        for (int mt = 0; mt < 4; ++mt) {
#pragma unroll
            for (int r = 0; r < 4; ++r) {
                float v = acc1[mt][nt][r] + bias;
                v = 0.5f * v * (1.f + erff(v * 0.70710678118654752f));
                hbuf[(mt * 16 + lq * 4 + r) * HBST + nn] = f2bf(v);
            }
        }
    }
    __syncthreads();

    // ---- GEMM2: out[64][128] = hid[64,256] @ w2^T + b2, wave owns 32 cols
    f4x acc2[4][2];
#pragma unroll
    for (int mt = 0; mt < 4; ++mt)
#pragma unroll
        for (int nt = 0; nt < 2; ++nt) acc2[mt][nt] = (f4x){0.f, 0.f, 0.f, 0.f};

    const int nw2 = wave * 32;
    for (int ks = 0; ks < 8; ++ks) {
        const int k0 = ks * 32 + lq * 8;
        s8x af[4], bf2v[2];
#pragma unroll
        for (int mt = 0; mt < 4; ++mt)
            af[mt] = *(const s8x*)&hbuf[(mt * 16 + lr) * HBST + k0];
#pragma unroll
        for (int nt = 0; nt < 2; ++nt)
            bf2v[nt] = *(const s8x*)&w2b[(size_t)(nw2 + nt * 16 + lr) * 256 + k0];
#pragma unroll
        for (int mt = 0; mt < 4; ++mt)
#pragma unroll
            for (int nt = 0; nt < 2; ++nt)
                acc2[mt][nt] = __builtin_amdgcn_mfma_f32_16x16x32_bf16(
                    af[mt], bf2v[nt], acc2[mt][nt], 0, 0, 0);
    }
    // epilogue: bias + store fp32
#pragma unroll
    for (int nt = 0; nt < 2; ++nt) {
        int n2 = nw2 + nt * 16 + lr;
        float bias = b2[n2];
#pragma unroll
        for (int mt = 0; mt < 4; ++mt) {
#pragma unroll
            for (int r = 0; r < 4; ++r) {
                int gn = node0 + mt * 16 + lq * 4 + r;
                if (gn < n) out[(size_t)gn * DIM + n2] = acc2[mt][nt][r] + bias;
            }
        }
    }
}

// ---------------------------------------------------------------------------
extern "C" void kernel_launch(void* const* d_in, const int* in_sizes, int n_in,
                              void* d_out, int out_size, void* d_ws, size_t ws_size,
                              hipStream_t stream) {
    const float* x   = (const float*)d_in[0];
    const float* R   = (const float*)d_in[1];
    const int*   src = (const int*)d_in[2];
    const int*   dst = (const int*)d_in[3];
    const float* w1  = (const float*)d_in[4];
    const float* b1  = (const float*)d_in[5];
    const float* w2  = (const float*)d_in[6];
    const float* b2  = (const float*)d_in[7];
    float* out = (float*)d_out;

    const int N = in_sizes[0] / DIM;   // 100000
    const int E = in_sizes[2];         // 1600000

    const int nbuck = (N + 127) >> 7;          // 782
    const int chunk = (E + 255) / 256;         // 6250
    const int nScan = nbuck * 256;             // 200192
    const int nScan2 = 2 * nScan;              // TD+TS concatenated
    const int nbScan2 = (nScan2 + 1023) / 1024;

    // ws layout:
    // hA [N*128 bf16] | hM [N*128 bf16]  (hM aliased by pairs[E u64] + srcval[E int])
    // rdeg [N f32] | rowstart [N+1] | esrc [E] | TD [nScan] | TS [nScan] |
    // bsums [1024] | w1b [32768 us] | w2b [32768 us]
    unsigned short* hA = (unsigned short*)d_ws;
    unsigned short* hM = hA + (size_t)N * DIM;
    unsigned long long* pairs = (unsigned long long*)hM;   // scratch, dead before gather1
    int* srcval = (int*)(pairs + E);
    float* rdeg     = (float*)(hM + (size_t)N * DIM);
    int*   rowstart = (int*)(rdeg + N);
    int*   esrc     = rowstart + (N + 1);
    int*   TD       = esrc + E;
    int*   TS       = TD + nScan;              // contiguous after TD (required by fused scan)
    int*   bsums    = TS + nScan;
    unsigned short* w1b = (unsigned short*)(bsums + 1024);
    unsigned short* w2b = w1b + 32768;

    const int BLK = 256;

    // 1) CSR + degree build via bucketed counting sort (no global atomics)
    hist_kernel<<<256, BLK, 0, stream>>>(src, dst, TD, TS, E, nbuck, chunk);
    scan_blocks<<<nbScan2, BLK, 0, stream>>>(TD, TD, bsums, nScan2);
    scan_sums<<<1, BLK, 0, stream>>>(bsums, nbScan2);
    scan_add<<<(nScan2 + BLK - 1) / BLK, BLK, 0, stream>>>(TD, bsums, nScan2, nScan, E);
    scatter_edges<<<256, BLK, 0, stream>>>(src, dst, TD, TS, pairs, srcval, E, nbuck, chunk);
    finalize_kernel<<<nbuck, BLK, 0, stream>>>(pairs, TD, srcval, TS, rowstart, esrc, rdeg, E, nbuck, N);

    // 2) forward rotation into hA (bf16) + weights -> bf16 (tail blocks)
    const int nbRot = ((size_t)N * 8 + BLK - 1) / BLK;
    rot_cvt_kernel<<<nbRot + 16, BLK, 0, stream>>>(x, R, hA, w1, w2, w1b, w2b, N, nbRot);

    // 3) propagation rounds as gathers (bf16 rows, coef = rdeg[s]*rdeg[d])
    gather_kernel<<<(N + 7) / 8, BLK, 0, stream>>>(hA, esrc, rdeg, rowstart, hM, N);
    gather_kernel<<<(N + 7) / 8, BLK, 0, stream>>>(hM, esrc, rdeg, rowstart, hA, N);

    // 4) fused inverse rotation + FFN (bf16 MFMA) -> out
    ffn_kernel<<<(N + 63) / 64, BLK, 0, stream>>>(hA, R, w1b, b1, w2b, b2, out, N);
}